// Round 3
// baseline (7541.615 us; speedup 1.0000x reference)
//
#include <hip/hip_runtime.h>
#include <hip/hip_bf16.h>

typedef float f4 __attribute__((ext_vector_type(4)));

// ---------------------------------------------------------------------------
// Stem: 512x512x3 --7x7 s2 pad2--> 256x256x64, ReLU.
// ---------------------------------------------------------------------------
__global__ __launch_bounds__(256) void stem_kernel(
    const float* __restrict__ in, const float* __restrict__ w,
    float* __restrict__ out)
{
  __shared__ float in_lds[37 * 37 * 3];   // 4107 floats
  __shared__ float w_lds[7 * 7 * 3 * 64]; // 9408 floats
  const int tid = threadIdx.x;
  const int ty0 = (blockIdx.x >> 4) * 16;
  const int tx0 = (blockIdx.x & 15) * 16;

  for (int idx = tid; idx < 9408; idx += 256) w_lds[idx] = w[idx];
  for (int idx = tid; idx < 4107; idx += 256) {
    int ci = idx % 3;
    int rem = idx / 3;
    int ix = rem % 37, iy = rem / 37;
    int gy = ty0 * 2 - 2 + iy, gx = tx0 * 2 - 2 + ix;
    float v = 0.f;
    if ((unsigned)gy < 512u && (unsigned)gx < 512u)
      v = in[(gy * 512 + gx) * 3 + ci];
    in_lds[idx] = v;
  }
  __syncthreads();

  const int co = (tid & 15) * 4;
  const int py = tid >> 4;
  f4 acc[16];
#pragma unroll
  for (int px = 0; px < 16; ++px) acc[px] = (f4)0.f;

  for (int ky = 0; ky < 7; ++ky)
    for (int kx = 0; kx < 7; ++kx)
#pragma unroll
      for (int ci = 0; ci < 3; ++ci) {
        f4 wv = *(const f4*)&w_lds[(((ky * 7 + kx) * 3) + ci) * 64 + co];
        const float* ip = &in_lds[((2 * py + ky) * 37 + kx) * 3 + ci];
#pragma unroll
        for (int px = 0; px < 16; ++px) {
          float iv = ip[px * 6];
          acc[px] += iv * wv;
        }
      }

#pragma unroll
  for (int px = 0; px < 16; ++px) {
    int oy = ty0 + py, ox = tx0 + px;
    f4 o = acc[px];
#pragma unroll
    for (int c = 0; c < 4; ++c) o[c] = fmaxf(o[c], 0.f);
    *(f4*)&out[(oy * 256 + ox) * 64 + co] = o;
  }
}

// ---------------------------------------------------------------------------
// 3x3 implicit-GEMM conv, NHWC fp32. Block tile 128 pix x 128 co, 256 thr,
// 8x8 outputs/thread. Software-pipelined: chunk c+1's global loads are issued
// right after the LDS-ready barrier so they fly during chunk c's FMA phase.
// gridDim.z splits C_in into slices of ci_per_z (partials at z*npix*C_out).
// ---------------------------------------------------------------------------
__global__ __launch_bounds__(256, 2) void conv128(
    const float* __restrict__ in, const float* __restrict__ w,
    float* __restrict__ pout,
    int H_in, int W_in, int C_in, int wshift, int C_out,
    int stride, int pad, int ci_per_z, int npix, int relu)
{
  __shared__ __align__(16) float As[128][36];  // [pix][ci] (+4 pad)
  __shared__ __align__(16) float Bs[32][128];  // [ci][co]
  const int tid = threadIdx.x;
  const int pix_base = blockIdx.x * 128;
  const int co_base = blockIdx.y * 128;
  const int ci_z0 = blockIdx.z * ci_per_z;
  const int ci_end = ci_z0 + ci_per_z;
  const int wmask = (1 << wshift) - 1;

  const int tx = tid & 15, ty = tid >> 4;

  // A staging decode: 128x32 floats = 1024 f4, 4 per thread
  int a_pix[4], a_c4[4], a_ys[4], a_xs[4];
#pragma unroll
  for (int q = 0; q < 4; ++q) {
    int f = q * 256 + tid;
    a_pix[q] = f >> 3; a_c4[q] = f & 7;
    int p = pix_base + a_pix[q];
    a_ys[q] = (p >> wshift) * stride - pad;
    a_xs[q] = (p & wmask) * stride - pad;
  }
  // B staging decode: 32x128 floats = 1024 f4, 4 per thread
  int b_off[4];
#pragma unroll
  for (int q = 0; q < 4; ++q) {
    int f = q * 256 + tid;
    b_off[q] = (f >> 5) * C_out + (f & 31) * 4;
  }
  int b_lrow[4], b_lco[4];
#pragma unroll
  for (int q = 0; q < 4; ++q) {
    int f = q * 256 + tid;
    b_lrow[q] = f >> 5; b_lco[q] = (f & 31) * 4;
  }

  f4 acc0[8], acc1[8];
#pragma unroll
  for (int i = 0; i < 8; ++i) { acc0[i] = (f4)0.f; acc1[i] = (f4)0.f; }

#define PREFETCH(KY, KX, CI, RA, RB)                                          \
  do {                                                                        \
    _Pragma("unroll")                                                         \
    for (int q = 0; q < 4; ++q) {                                             \
      int iy = a_ys[q] + (KY);                                                \
      int ix = a_xs[q] + (KX);                                                \
      f4 av = (f4)0.f;                                                        \
      if (((unsigned)iy < (unsigned)H_in) && ((unsigned)ix < (unsigned)W_in)) \
        av = *(const f4*)(in + (size_t)(iy * W_in + ix) * C_in +              \
                          (CI) + a_c4[q] * 4);                                \
      RA[q] = av;                                                             \
    }                                                                         \
    const float* bb = w + (size_t)(((KY)*3 + (KX)) * C_in + (CI)) * C_out +   \
                      co_base;                                                \
    _Pragma("unroll")                                                         \
    for (int q = 0; q < 4; ++q) RB[q] = *(const f4*)(bb + b_off[q]);          \
  } while (0)

  const int nc = ci_per_z >> 5;
  const int total = 9 * nc;
  int cky = 0, ckx = 0, cci = ci_z0;

  f4 ra[4], rb[4];
  PREFETCH(0, 0, ci_z0, ra, rb);

  for (int c = 0; c < total; ++c) {
    __syncthreads();  // previous compute done before LDS overwrite
#pragma unroll
    for (int q = 0; q < 4; ++q) *(f4*)&As[a_pix[q]][a_c4[q] * 4] = ra[q];
#pragma unroll
    for (int q = 0; q < 4; ++q) *(f4*)&Bs[b_lrow[q]][b_lco[q]] = rb[q];
    __syncthreads();  // LDS ready

    // advance chunk indices (uniform)
    int nky = cky, nkx = ckx, nci = cci + 32;
    if (nci == ci_end) { nci = ci_z0; nkx++; if (nkx == 3) { nkx = 0; nky++; } }
    f4 na[4], nb[4];
    if (c + 1 < total) PREFETCH(nky, nkx, nci, na, nb);

#pragma unroll
    for (int kk = 0; kk < 32; kk += 4) {
      f4 a[8];
#pragma unroll
      for (int i = 0; i < 8; ++i) a[i] = *(const f4*)&As[ty * 8 + i][kk];
#pragma unroll
      for (int j = 0; j < 4; ++j) {
        f4 b0 = *(const f4*)&Bs[kk + j][tx * 8];
        f4 b1 = *(const f4*)&Bs[kk + j][tx * 8 + 4];
#pragma unroll
        for (int i = 0; i < 8; ++i) {
          float av = a[i][j];
          acc0[i] += av * b0;
          acc1[i] += av * b1;
        }
      }
    }
    if (c + 1 < total) {
#pragma unroll
      for (int q = 0; q < 4; ++q) { ra[q] = na[q]; rb[q] = nb[q]; }
    }
    cky = nky; ckx = nkx; cci = nci;
  }
#undef PREFETCH

  float* dst = pout + (size_t)blockIdx.z * npix * C_out;
#pragma unroll
  for (int i = 0; i < 8; ++i) {
    int p = pix_base + ty * 8 + i;
    f4 o0 = acc0[i], o1 = acc1[i];
    if (relu) {
#pragma unroll
      for (int c = 0; c < 4; ++c) { o0[c] = fmaxf(o0[c], 0.f); o1[c] = fmaxf(o1[c], 0.f); }
    }
    *(f4*)&dst[(size_t)p * C_out + co_base + tx * 8] = o0;
    *(f4*)&dst[(size_t)p * C_out + co_base + tx * 8 + 4] = o1;
  }
}

// ---------------------------------------------------------------------------
// Sum Z partial slices (f4-vectorized) + optional ReLU.
// ---------------------------------------------------------------------------
__global__ __launch_bounds__(256) void reduce_relu_kernel(
    const float* __restrict__ p, float* __restrict__ out, int n4, int Z, int relu)
{
  int idx = blockIdx.x * 256 + threadIdx.x;
  if (idx >= n4) return;
  const f4* pv = (const f4*)p;
  f4 s = pv[idx];
  for (int z = 1; z < Z; ++z) s += pv[(size_t)z * n4 + idx];
  if (relu) {
#pragma unroll
    for (int c = 0; c < 4; ++c) s[c] = fmaxf(s[c], 0.f);
  }
  ((f4*)out)[idx] = s;
}

// ---------------------------------------------------------------------------
// 1x1 conv with optional fused nearest-neighbor up2 add.
// ---------------------------------------------------------------------------
__global__ __launch_bounds__(256) void conv1x1_kernel(
    const float* __restrict__ in, const float* __restrict__ w,
    const float* __restrict__ res, float* __restrict__ out,
    int C_in, int C_out, int wshift, int add_up2)
{
  const int tid = threadIdx.x;
  const int co = blockIdx.y * 64 + (tid & 63);
  const int pg = tid >> 6;
  const int p_base = blockIdx.x * 16 + pg * 4;
  const int wmask = (1 << wshift) - 1;

  float acc[4] = {0.f, 0.f, 0.f, 0.f};
  for (int ci = 0; ci < C_in; ci += 4) {
    float w0 = w[(ci + 0) * C_out + co];
    float w1 = w[(ci + 1) * C_out + co];
    float w2 = w[(ci + 2) * C_out + co];
    float w3 = w[(ci + 3) * C_out + co];
#pragma unroll
    for (int q = 0; q < 4; ++q) {
      f4 iv = *(const f4*)&in[(p_base + q) * C_in + ci];
      acc[q] += iv[0] * w0 + iv[1] * w1 + iv[2] * w2 + iv[3] * w3;
    }
  }
#pragma unroll
  for (int q = 0; q < 4; ++q) {
    int p = p_base + q;
    float v = acc[q];
    if (add_up2) {
      int oy = p >> wshift, ox = p & wmask;
      v += res[(((oy >> 1) << (wshift - 1)) + (ox >> 1)) * C_out + co];
    }
    out[p * C_out + co] = v;
  }
}

// ---------------------------------------------------------------------------
// obj head (1x1, 256->1) + sigmoid.
// ---------------------------------------------------------------------------
__global__ __launch_bounds__(256) void obj_sigmoid_kernel(
    const float* __restrict__ t, const float* __restrict__ wobj,
    float* __restrict__ scores)
{
  __shared__ float wl[256];
  const int tid = threadIdx.x;
  wl[tid] = wobj[tid];
  __syncthreads();
  const int p = blockIdx.x * 256 + tid;
  float acc = 0.f;
  for (int ci = 0; ci < 256; ci += 4) {
    f4 tv = *(const f4*)&t[p * 256 + ci];
    acc += tv[0] * wl[ci] + tv[1] * wl[ci + 1] + tv[2] * wl[ci + 2] + tv[3] * wl[ci + 3];
  }
  scores[p] = 1.f / (1.f + expf(-acc));
}

// ---------------------------------------------------------------------------
// Greedy NMS, single wave (64 lanes), 100 iterations, faithful to reference.
// Lane l owns grid row i=l (i = k>>6). Scores in LDS with row stride 68
// (16B-aligned, b128 reads hit the 8-cyc/KB LDS optimum). Per-lane cached
// row argmax; only |i-si|<=6 rows rescan after suppression; global argmax
// via 6-step shuffle butterfly. No multi-wave barriers.
// ---------------------------------------------------------------------------
__global__ __launch_bounds__(64) void nms_kernel(
    const float* __restrict__ scores, float* __restrict__ out)
{
  __shared__ __align__(16) float sw[64 * 68];
  const int lane = threadIdx.x;  // = row i
  const float inv63 = 1.0f / 63.0f;

  // load: iteration r = row, lane = j (coalesced global, banks rotate via +68)
#pragma unroll
  for (int r = 0; r < 64; ++r)
    sw[r * 68 + lane] = scores[r * 64 + lane];
  __syncthreads();

  // initial row argmax (first-index tiebreak via strict >)
  float bv = -3.0e38f;
  int bj = 0;
  {
    const float* row = &sw[lane * 68];
#pragma unroll
    for (int jq = 0; jq < 16; ++jq) {
      f4 v4 = *(const f4*)&row[jq * 4];
#pragma unroll
      for (int c = 0; c < 4; ++c) {
        float v = v4[c];
        int j = jq * 4 + c;
        if (v > bv) { bv = v; bj = j; }
      }
    }
  }

  for (int it = 0; it < 100; ++it) {
    // global argmax: prefer larger value, tie -> smaller flat index k
    float v = bv;
    int k = (lane << 6) | bj;
#pragma unroll
    for (int off = 32; off > 0; off >>= 1) {
      float ov = __shfl_down(v, off);
      int ok = __shfl_down(k, off);
      if (ov > v || (ov == v && ok < k)) { v = ov; k = ok; }
    }
    v = __shfl(v, 0);
    k = __shfl(k, 0);

    const int si = k >> 6, sj = k & 63;
    const float ay = sj * inv63, ax = si * inv63;
    const float a0 = fmaxf(ay - 0.05f, 0.f);
    const float a1 = fmaxf(ax - 0.05f, 0.f);
    const float a2 = fminf(ay + 0.05f, 1.f);
    const float a3 = fminf(ax + 0.05f, 1.f);
    const float barea = (a2 - a0) * (a3 - a1);

    if (lane == 0) {
      bool valid = v > -5.0e29f;
      out[it * 4 + 0] = valid ? a0 : 0.f;
      out[it * 4 + 1] = valid ? a1 : 0.f;
      out[it * 4 + 2] = valid ? a2 : 0.f;
      out[it * 4 + 3] = valid ? a3 : 0.f;
      out[400 + it] = valid ? v : 0.f;
    }

    // suppress the 13x13 patch around (si,sj): 169 entries, 3 passes
#pragma unroll
    for (int pass = 0; pass < 3; ++pass) {
      int e = pass * 64 + lane;
      if (e < 169) {
        int i = si - 6 + e / 13;
        int j = sj - 6 + e % 13;
        if ((unsigned)i < 64u && (unsigned)j < 64u) {
          float cy = j * inv63, cx = i * inv63;
          float c0 = fmaxf(cy - 0.05f, 0.f), c1 = fmaxf(cx - 0.05f, 0.f);
          float c2 = fminf(cy + 0.05f, 1.f), c3 = fminf(cx + 0.05f, 1.f);
          float yy1 = fmaxf(a0, c0), xx1 = fmaxf(a1, c1);
          float yy2 = fminf(a2, c2), xx2 = fminf(a3, c3);
          float inter = fmaxf(yy2 - yy1, 0.f) * fmaxf(xx2 - xx1, 0.f);
          float carea = (c2 - c0) * (c3 - c1);
          float iou = inter / (barea + carea - inter + 1e-9f);
          if (iou > 0.5f) sw[i * 68 + j] = -1.0e30f;
        }
      }
    }
    __syncthreads();  // single wave: cheap, guarantees LDS write->read order

    // rescan only affected rows; others keep cached (bv,bj)
    int d = lane - si;
    if (d < 0) d = -d;
    if (d <= 6) {
      const float* row = &sw[lane * 68];
      float nv = -3.0e38f;
      int nj = 0;
#pragma unroll
      for (int jq = 0; jq < 16; ++jq) {
        f4 v4 = *(const f4*)&row[jq * 4];
#pragma unroll
        for (int c = 0; c < 4; ++c) {
          float vv = v4[c];
          int j = jq * 4 + c;
          if (vv > nv) { nv = vv; nj = j; }
        }
      }
      bv = nv; bj = nj;
    }
  }
}

// ---------------------------------------------------------------------------
extern "C" void kernel_launch(void* const* d_in, const int* in_sizes, int n_in,
                              void* d_out, int out_size, void* d_ws, size_t ws_size,
                              hipStream_t stream) {
  const float* x      = (const float*)d_in[0];
  const float* w_stem = (const float*)d_in[1];
  const float* w_c2   = (const float*)d_in[2];
  const float* w_c3   = (const float*)d_in[3];
  const float* w_c4   = (const float*)d_in[4];
  const float* w_c5   = (const float*)d_in[5];
  const float* l3     = (const float*)d_in[6];
  const float* l4     = (const float*)d_in[7];
  const float* l5     = (const float*)d_in[8];
  const float* o3w    = (const float*)d_in[9];
  const float* w_rpn  = (const float*)d_in[12];
  const float* w_obj  = (const float*)d_in[13];
  float* out = (float*)d_out;
  float* ws = (float*)d_ws;

  float* S   = ws;              // 256*256*64   = 4194304 floats
  float* C2  = S   + 4194304;   // 128*128*256  = 4194304
  float* C3  = C2  + 4194304;   // 64*64*512    = 2097152
  float* C4  = C3  + 2097152;   // 32*32*1024   = 1048576
  float* C5  = C4  + 1048576;   // 16*16*2048   = 524288
  float* P5  = C5  + 524288;    // 16*16*256    = 65536
  float* P4  = P5  + 65536;     // 32*32*256    = 262144
  float* P3P = P4  + 262144;    // 64*64*256    = 1048576
  float* P3  = P3P + 1048576;   // 1048576
  float* T   = P3  + 1048576;   // 1048576
  float* SC  = T   + 1048576;   // 4096

  // backbone
  stem_kernel<<<256, 256, 0, stream>>>(x, w_stem, S);
  conv128<<<dim3(128, 2, 1), 256, 0, stream>>>(
      S, w_c2, C2, 256, 256, 64, 7, 256, 2, 0, 64, 16384, 1);
  conv128<<<dim3(32, 4, 2), 256, 0, stream>>>(
      C2, w_c3, S, 128, 128, 256, 6, 512, 2, 0, 128, 4096, 0);
  reduce_relu_kernel<<<2048, 256, 0, stream>>>(S, C3, 524288, 2, 1);
  conv128<<<dim3(8, 8, 8), 256, 0, stream>>>(
      C3, w_c4, S, 64, 64, 512, 5, 1024, 2, 0, 64, 1024, 0);
  reduce_relu_kernel<<<1024, 256, 0, stream>>>(S, C4, 262144, 8, 1);
  conv128<<<dim3(2, 16, 16), 256, 0, stream>>>(
      C4, w_c5, S, 32, 32, 1024, 4, 2048, 2, 0, 64, 256, 0);
  reduce_relu_kernel<<<512, 256, 0, stream>>>(S, C5, 131072, 16, 1);
  // FPN laterals (+ fused up2 add)
  conv1x1_kernel<<<dim3(16, 4), 256, 0, stream>>>(C5, l5, nullptr, P5, 2048, 256, 4, 0);
  conv1x1_kernel<<<dim3(64, 4), 256, 0, stream>>>(C4, l4, P5, P4, 1024, 256, 5, 1);
  conv1x1_kernel<<<dim3(256, 4), 256, 0, stream>>>(C3, l3, P4, P3P, 512, 256, 6, 1);
  // o3 conv (no relu)
  conv128<<<dim3(32, 2, 8), 256, 0, stream>>>(
      P3P, o3w, S, 64, 64, 256, 6, 256, 1, 1, 32, 4096, 0);
  reduce_relu_kernel<<<1024, 256, 0, stream>>>(S, P3, 262144, 8, 0);
  // rpn shared conv (relu)
  conv128<<<dim3(32, 2, 8), 256, 0, stream>>>(
      P3, w_rpn, S, 64, 64, 256, 6, 256, 1, 1, 32, 4096, 0);
  reduce_relu_kernel<<<1024, 256, 0, stream>>>(S, T, 262144, 8, 1);
  // obj head + sigmoid, then NMS
  obj_sigmoid_kernel<<<16, 256, 0, stream>>>(T, w_obj, SC);
  nms_kernel<<<1, 64, 0, stream>>>(SC, out);
}

// Round 4
// 1085.431 us; speedup vs baseline: 6.9480x; 6.9480x over previous
//
#include <hip/hip_runtime.h>
#include <hip/hip_bf16.h>

typedef float f4 __attribute__((ext_vector_type(4)));

// ---------------------------------------------------------------------------
// Stem: 512x512x3 --7x7 s2 pad2--> 256x256x64, ReLU.
// ---------------------------------------------------------------------------
__global__ __launch_bounds__(256) void stem_kernel(
    const float* __restrict__ in, const float* __restrict__ w,
    float* __restrict__ out)
{
  __shared__ float in_lds[37 * 37 * 3];   // 4107 floats
  __shared__ float w_lds[7 * 7 * 3 * 64]; // 9408 floats
  const int tid = threadIdx.x;
  const int ty0 = (blockIdx.x >> 4) * 16;
  const int tx0 = (blockIdx.x & 15) * 16;

  for (int idx = tid; idx < 9408; idx += 256) w_lds[idx] = w[idx];
  for (int idx = tid; idx < 4107; idx += 256) {
    int ci = idx % 3;
    int rem = idx / 3;
    int ix = rem % 37, iy = rem / 37;
    int gy = ty0 * 2 - 2 + iy, gx = tx0 * 2 - 2 + ix;
    float v = 0.f;
    if ((unsigned)gy < 512u && (unsigned)gx < 512u)
      v = in[(gy * 512 + gx) * 3 + ci];
    in_lds[idx] = v;
  }
  __syncthreads();

  const int co = (tid & 15) * 4;
  const int py = tid >> 4;
  f4 acc[16];
#pragma unroll
  for (int px = 0; px < 16; ++px) acc[px] = (f4)0.f;

  for (int ky = 0; ky < 7; ++ky)
    for (int kx = 0; kx < 7; ++kx)
#pragma unroll
      for (int ci = 0; ci < 3; ++ci) {
        f4 wv = *(const f4*)&w_lds[(((ky * 7 + kx) * 3) + ci) * 64 + co];
        const float* ip = &in_lds[((2 * py + ky) * 37 + kx) * 3 + ci];
#pragma unroll
        for (int px = 0; px < 16; ++px) {
          float iv = ip[px * 6];
          acc[px] += iv * wv;
        }
      }

#pragma unroll
  for (int px = 0; px < 16; ++px) {
    int oy = ty0 + py, ox = tx0 + px;
    f4 o = acc[px];
#pragma unroll
    for (int c = 0; c < 4; ++c) o[c] = fmaxf(o[c], 0.f);
    *(f4*)&out[(oy * 256 + ox) * 64 + co] = o;
  }
}

// ---------------------------------------------------------------------------
// 3x3 implicit-GEMM conv, NHWC fp32. Block tile 128 pix x 128 co, 256 thr,
// 8x8 outputs/thread. R2 structure (NO register pipeline — R3 post-mortem:
// cross-chunk reg prefetch caused 3.7 GB of scratch spill traffic).
// B-fragment cols are tx*4 and 64+tx*4: LDS banks stride 16 B -> 2-way
// aliasing = free (the tx*8 mapping was a 4-way conflict, 9.4M cycles).
// gridDim.z splits C_in into slices of ci_per_z (partials at z*npix*C_out).
// ---------------------------------------------------------------------------
__global__ __launch_bounds__(256, 2) void conv128(
    const float* __restrict__ in, const float* __restrict__ w,
    float* __restrict__ pout,
    int H_in, int W_in, int C_in, int wshift, int C_out,
    int stride, int pad, int ci_per_z, int npix, int relu)
{
  __shared__ __align__(16) float As[128][36];  // [pix][ci] (+4 pad)
  __shared__ __align__(16) float Bs[32][128];  // [ci][co]
  const int tid = threadIdx.x;
  const int pix_base = blockIdx.x * 128;
  const int co_base = blockIdx.y * 128;
  const int ci_z0 = blockIdx.z * ci_per_z;
  const int wmask = (1 << wshift) - 1;

  const int tx = tid & 15, ty = tid >> 4;

  // A staging decode: 128x32 floats = 1024 f4, 4 per thread
  int a_pix[4], a_c4[4], a_oy[4], a_ox[4];
#pragma unroll
  for (int q = 0; q < 4; ++q) {
    int f = q * 256 + tid;
    a_pix[q] = f >> 3; a_c4[q] = f & 7;
    int p = pix_base + a_pix[q];
    a_oy[q] = p >> wshift; a_ox[q] = p & wmask;
  }
  // B staging decode: 32x128 floats = 1024 f4, 4 per thread
  int b_row[4], b_co4[4];
#pragma unroll
  for (int q = 0; q < 4; ++q) {
    int f = q * 256 + tid;
    b_row[q] = f >> 5; b_co4[q] = f & 31;
  }

  f4 acc0[8], acc1[8];
#pragma unroll
  for (int i = 0; i < 8; ++i) { acc0[i] = (f4)0.f; acc1[i] = (f4)0.f; }

  for (int ky = 0; ky < 3; ++ky) {
    for (int kx = 0; kx < 3; ++kx) {
      const float* aptr[4];
      bool aval[4];
#pragma unroll
      for (int q = 0; q < 4; ++q) {
        int iy = a_oy[q] * stride - pad + ky;
        int ix = a_ox[q] * stride - pad + kx;
        aval[q] = ((unsigned)iy < (unsigned)H_in) && ((unsigned)ix < (unsigned)W_in);
        aptr[q] = in + (size_t)(iy * W_in + ix) * C_in + a_c4[q] * 4;
      }
      const float* bbase = w + (size_t)((ky * 3 + kx) * C_in) * C_out + co_base;

      for (int ci = ci_z0; ci < ci_z0 + ci_per_z; ci += 32) {
        __syncthreads();  // previous compute done before overwrite
#pragma unroll
        for (int q = 0; q < 4; ++q) {
          f4 av = (f4)0.f;
          if (aval[q]) av = *(const f4*)(aptr[q] + ci);
          *(f4*)&As[a_pix[q]][a_c4[q] * 4] = av;
        }
#pragma unroll
        for (int q = 0; q < 4; ++q) {
          *(f4*)&Bs[b_row[q]][b_co4[q] * 4] =
              *(const f4*)(bbase + (size_t)(ci + b_row[q]) * C_out + b_co4[q] * 4);
        }
        __syncthreads();
#pragma unroll
        for (int kk = 0; kk < 32; kk += 4) {
          f4 a[8];
#pragma unroll
          for (int i = 0; i < 8; ++i) a[i] = *(const f4*)&As[ty * 8 + i][kk];
#pragma unroll
          for (int j = 0; j < 4; ++j) {
            f4 b0 = *(const f4*)&Bs[kk + j][tx * 4];
            f4 b1 = *(const f4*)&Bs[kk + j][64 + tx * 4];
#pragma unroll
            for (int i = 0; i < 8; ++i) {
              float av = a[i][j];
              acc0[i] += av * b0;
              acc1[i] += av * b1;
            }
          }
        }
      }
    }
  }

  float* dst = pout + (size_t)blockIdx.z * npix * C_out;
#pragma unroll
  for (int i = 0; i < 8; ++i) {
    int p = pix_base + ty * 8 + i;
    f4 o0 = acc0[i], o1 = acc1[i];
    if (relu) {
#pragma unroll
      for (int c = 0; c < 4; ++c) { o0[c] = fmaxf(o0[c], 0.f); o1[c] = fmaxf(o1[c], 0.f); }
    }
    *(f4*)&dst[(size_t)p * C_out + co_base + tx * 4] = o0;
    *(f4*)&dst[(size_t)p * C_out + co_base + 64 + tx * 4] = o1;
  }
}

// ---------------------------------------------------------------------------
// Sum Z partial slices (f4-vectorized) + optional ReLU.
// ---------------------------------------------------------------------------
__global__ __launch_bounds__(256) void reduce_relu_kernel(
    const float* __restrict__ p, float* __restrict__ out, int n4, int Z, int relu)
{
  int idx = blockIdx.x * 256 + threadIdx.x;
  if (idx >= n4) return;
  const f4* pv = (const f4*)p;
  f4 s = pv[idx];
  for (int z = 1; z < Z; ++z) s += pv[(size_t)z * n4 + idx];
  if (relu) {
#pragma unroll
    for (int c = 0; c < 4; ++c) s[c] = fmaxf(s[c], 0.f);
  }
  ((f4*)out)[idx] = s;
}

// ---------------------------------------------------------------------------
// 1x1-conv GEMM tile: 64 pix x 64 co, 256 thr, 4 pix x 4 co per thread.
// gridDim.z splits C_in (partials at z*npix*C_out). C_out==256 fixed use.
// As2 transposed [ci][pix+4pad] so compute reads are f4 along pixels.
// ---------------------------------------------------------------------------
__global__ __launch_bounds__(256) void gemm64(
    const float* __restrict__ in, const float* __restrict__ w,
    float* __restrict__ pout, int C_in, int C_out, int ci_per_z, int npix)
{
  __shared__ __align__(16) float As2[32][68];
  __shared__ __align__(16) float Bs[32][64];
  const int tid = threadIdx.x;
  const int pix_base = blockIdx.x * 64;
  const int co_base = blockIdx.y * 64;
  const int ci_z0 = blockIdx.z * ci_per_z;
  const int tx = tid & 15, ty = tid >> 4;

  // A staging: 64 pix x 32 ci = 512 f4, 2/thread (global-coalesced)
  int ga_pix[2], ga_c4[2];
#pragma unroll
  for (int q = 0; q < 2; ++q) {
    int f = q * 256 + tid;
    ga_pix[q] = f >> 3; ga_c4[q] = f & 7;
  }
  // B staging: 32 x 64 = 512 f4, 2/thread
  int gb_row[2], gb_c4[2];
#pragma unroll
  for (int q = 0; q < 2; ++q) {
    int f = q * 256 + tid;
    gb_row[q] = f >> 4; gb_c4[q] = f & 15;
  }

  f4 acc[4];
#pragma unroll
  for (int i = 0; i < 4; ++i) acc[i] = (f4)0.f;

  for (int ci = ci_z0; ci < ci_z0 + ci_per_z; ci += 32) {
    __syncthreads();
#pragma unroll
    for (int q = 0; q < 2; ++q) {
      f4 av = *(const f4*)&in[(size_t)(pix_base + ga_pix[q]) * C_in + ci + ga_c4[q] * 4];
#pragma unroll
      for (int u = 0; u < 4; ++u) As2[ga_c4[q] * 4 + u][ga_pix[q]] = av[u];
    }
#pragma unroll
    for (int q = 0; q < 2; ++q) {
      *(f4*)&Bs[gb_row[q]][gb_c4[q] * 4] =
          *(const f4*)&w[(size_t)(ci + gb_row[q]) * C_out + co_base + gb_c4[q] * 4];
    }
    __syncthreads();
#pragma unroll
    for (int kk = 0; kk < 32; ++kk) {
      f4 a = *(const f4*)&As2[kk][ty * 4];
      f4 b = *(const f4*)&Bs[kk][tx * 4];
#pragma unroll
      for (int i = 0; i < 4; ++i) acc[i] += a[i] * b;
    }
  }

  float* dst = pout + (size_t)blockIdx.z * npix * C_out;
#pragma unroll
  for (int i = 0; i < 4; ++i)
    *(f4*)&dst[(size_t)(pix_base + ty * 4 + i) * C_out + co_base + tx * 4] = acc[i];
}

// ---------------------------------------------------------------------------
// Sum Z partial slices + optional fused nearest-up2 residual (C_out=256).
// ---------------------------------------------------------------------------
__global__ __launch_bounds__(256) void reduce_up2_kernel(
    const float* __restrict__ p, const float* __restrict__ res,
    float* __restrict__ out, int n4, int Z, int wshift)
{
  int idx = blockIdx.x * 256 + threadIdx.x;
  if (idx >= n4) return;
  const f4* pv = (const f4*)p;
  f4 s = pv[idx];
  for (int z = 1; z < Z; ++z) s += pv[(size_t)z * n4 + idx];
  if (res) {
    int pix = idx >> 6, c4 = idx & 63;
    int oy = pix >> wshift, ox = pix & ((1 << wshift) - 1);
    int rp = ((oy >> 1) << (wshift - 1)) + (ox >> 1);
    s += ((const f4*)res)[rp * 64 + c4];
  }
  ((f4*)out)[idx] = s;
}

// ---------------------------------------------------------------------------
// obj head (1x1, 256->1) + sigmoid. 4 threads/pixel, quad shuffle-reduce.
// ---------------------------------------------------------------------------
__global__ __launch_bounds__(256) void obj_sigmoid_kernel(
    const float* __restrict__ t, const float* __restrict__ wobj,
    float* __restrict__ scores)
{
  __shared__ float wl[256];
  const int tid = threadIdx.x;
  wl[tid] = wobj[tid];
  __syncthreads();
  const int pix = blockIdx.x * 64 + (tid >> 2);
  const int c0 = (tid & 3) * 64;
  float acc = 0.f;
#pragma unroll
  for (int k = 0; k < 16; ++k) {
    f4 tv = *(const f4*)&t[(size_t)pix * 256 + c0 + k * 4];
    const float* wp = &wl[c0 + k * 4];
    acc += tv[0] * wp[0] + tv[1] * wp[1] + tv[2] * wp[2] + tv[3] * wp[3];
  }
  acc += __shfl_xor(acc, 1);
  acc += __shfl_xor(acc, 2);
  if ((tid & 3) == 0) scores[pix] = 1.f / (1.f + expf(-acc));
}

// ---------------------------------------------------------------------------
// Greedy NMS, single wave, validated in R3 (kept byte-identical).
// ---------------------------------------------------------------------------
__global__ __launch_bounds__(64) void nms_kernel(
    const float* __restrict__ scores, float* __restrict__ out)
{
  __shared__ __align__(16) float sw[64 * 68];
  const int lane = threadIdx.x;  // = row i
  const float inv63 = 1.0f / 63.0f;

#pragma unroll
  for (int r = 0; r < 64; ++r)
    sw[r * 68 + lane] = scores[r * 64 + lane];
  __syncthreads();

  float bv = -3.0e38f;
  int bj = 0;
  {
    const float* row = &sw[lane * 68];
#pragma unroll
    for (int jq = 0; jq < 16; ++jq) {
      f4 v4 = *(const f4*)&row[jq * 4];
#pragma unroll
      for (int c = 0; c < 4; ++c) {
        float v = v4[c];
        int j = jq * 4 + c;
        if (v > bv) { bv = v; bj = j; }
      }
    }
  }

  for (int it = 0; it < 100; ++it) {
    float v = bv;
    int k = (lane << 6) | bj;
#pragma unroll
    for (int off = 32; off > 0; off >>= 1) {
      float ov = __shfl_down(v, off);
      int ok = __shfl_down(k, off);
      if (ov > v || (ov == v && ok < k)) { v = ov; k = ok; }
    }
    v = __shfl(v, 0);
    k = __shfl(k, 0);

    const int si = k >> 6, sj = k & 63;
    const float ay = sj * inv63, ax = si * inv63;
    const float a0 = fmaxf(ay - 0.05f, 0.f);
    const float a1 = fmaxf(ax - 0.05f, 0.f);
    const float a2 = fminf(ay + 0.05f, 1.f);
    const float a3 = fminf(ax + 0.05f, 1.f);
    const float barea = (a2 - a0) * (a3 - a1);

    if (lane == 0) {
      bool valid = v > -5.0e29f;
      out[it * 4 + 0] = valid ? a0 : 0.f;
      out[it * 4 + 1] = valid ? a1 : 0.f;
      out[it * 4 + 2] = valid ? a2 : 0.f;
      out[it * 4 + 3] = valid ? a3 : 0.f;
      out[400 + it] = valid ? v : 0.f;
    }

#pragma unroll
    for (int pass = 0; pass < 3; ++pass) {
      int e = pass * 64 + lane;
      if (e < 169) {
        int i = si - 6 + e / 13;
        int j = sj - 6 + e % 13;
        if ((unsigned)i < 64u && (unsigned)j < 64u) {
          float cy = j * inv63, cx = i * inv63;
          float c0 = fmaxf(cy - 0.05f, 0.f), c1 = fmaxf(cx - 0.05f, 0.f);
          float c2 = fminf(cy + 0.05f, 1.f), c3 = fminf(cx + 0.05f, 1.f);
          float yy1 = fmaxf(a0, c0), xx1 = fmaxf(a1, c1);
          float yy2 = fminf(a2, c2), xx2 = fminf(a3, c3);
          float inter = fmaxf(yy2 - yy1, 0.f) * fmaxf(xx2 - xx1, 0.f);
          float carea = (c2 - c0) * (c3 - c1);
          float iou = inter / (barea + carea - inter + 1e-9f);
          if (iou > 0.5f) sw[i * 68 + j] = -1.0e30f;
        }
      }
    }
    __syncthreads();

    int d = lane - si;
    if (d < 0) d = -d;
    if (d <= 6) {
      const float* row = &sw[lane * 68];
      float nv = -3.0e38f;
      int nj = 0;
#pragma unroll
      for (int jq = 0; jq < 16; ++jq) {
        f4 v4 = *(const f4*)&row[jq * 4];
#pragma unroll
        for (int c = 0; c < 4; ++c) {
          float vv = v4[c];
          int j = jq * 4 + c;
          if (vv > nv) { nv = vv; nj = j; }
        }
      }
      bv = nv; bj = nj;
    }
  }
}

// ---------------------------------------------------------------------------
extern "C" void kernel_launch(void* const* d_in, const int* in_sizes, int n_in,
                              void* d_out, int out_size, void* d_ws, size_t ws_size,
                              hipStream_t stream) {
  const float* x      = (const float*)d_in[0];
  const float* w_stem = (const float*)d_in[1];
  const float* w_c2   = (const float*)d_in[2];
  const float* w_c3   = (const float*)d_in[3];
  const float* w_c4   = (const float*)d_in[4];
  const float* w_c5   = (const float*)d_in[5];
  const float* l3     = (const float*)d_in[6];
  const float* l4     = (const float*)d_in[7];
  const float* l5     = (const float*)d_in[8];
  const float* o3w    = (const float*)d_in[9];
  const float* w_rpn  = (const float*)d_in[12];
  const float* w_obj  = (const float*)d_in[13];
  float* out = (float*)d_out;
  float* ws = (float*)d_ws;

  float* S   = ws;              // 256*256*64   = 4194304 floats (scratch/partials)
  float* C2  = S   + 4194304;   // 128*128*256  = 4194304
  float* C3  = C2  + 4194304;   // 64*64*512    = 2097152
  float* C4  = C3  + 2097152;   // 32*32*1024   = 1048576
  float* C5  = C4  + 1048576;   // 16*16*2048   = 524288
  float* P5  = C5  + 524288;    // 16*16*256    = 65536
  float* P4  = P5  + 65536;     // 32*32*256    = 262144
  float* P3P = P4  + 262144;    // 64*64*256    = 1048576
  float* P3  = P3P + 1048576;   // 1048576
  float* T   = P3  + 1048576;   // 1048576
  float* SC  = T   + 1048576;   // 4096

  // backbone
  stem_kernel<<<256, 256, 0, stream>>>(x, w_stem, S);
  conv128<<<dim3(128, 2, 1), 256, 0, stream>>>(
      S, w_c2, C2, 256, 256, 64, 7, 256, 2, 0, 64, 16384, 1);
  conv128<<<dim3(32, 4, 2), 256, 0, stream>>>(
      C2, w_c3, S, 128, 128, 256, 6, 512, 2, 0, 128, 4096, 0);
  reduce_relu_kernel<<<2048, 256, 0, stream>>>(S, C3, 524288, 2, 1);
  conv128<<<dim3(8, 8, 8), 256, 0, stream>>>(
      C3, w_c4, S, 64, 64, 512, 5, 1024, 2, 0, 64, 1024, 0);
  reduce_relu_kernel<<<1024, 256, 0, stream>>>(S, C4, 262144, 8, 1);
  conv128<<<dim3(2, 16, 16), 256, 0, stream>>>(
      C4, w_c5, S, 32, 32, 1024, 4, 2048, 2, 0, 64, 256, 0);
  reduce_relu_kernel<<<512, 256, 0, stream>>>(S, C5, 131072, 16, 1);
  // FPN laterals: gemm64 + Z-reduce with fused up2 add
  gemm64<<<dim3(4, 4, 8), 256, 0, stream>>>(C5, l5, S, 2048, 256, 256, 256);
  reduce_up2_kernel<<<64, 256, 0, stream>>>(S, nullptr, P5, 16384, 8, 4);
  gemm64<<<dim3(16, 4, 4), 256, 0, stream>>>(C4, l4, S, 1024, 256, 256, 1024);
  reduce_up2_kernel<<<256, 256, 0, stream>>>(S, P5, P4, 65536, 4, 5);
  gemm64<<<dim3(64, 4, 2), 256, 0, stream>>>(C3, l3, S, 512, 256, 256, 4096);
  reduce_up2_kernel<<<1024, 256, 0, stream>>>(S, P4, P3P, 262144, 2, 6);
  // o3 conv (no relu)
  conv128<<<dim3(32, 2, 8), 256, 0, stream>>>(
      P3P, o3w, S, 64, 64, 256, 6, 256, 1, 1, 32, 4096, 0);
  reduce_relu_kernel<<<1024, 256, 0, stream>>>(S, P3, 262144, 8, 0);
  // rpn shared conv (relu)
  conv128<<<dim3(32, 2, 8), 256, 0, stream>>>(
      P3, w_rpn, S, 64, 64, 256, 6, 256, 1, 1, 32, 4096, 0);
  reduce_relu_kernel<<<1024, 256, 0, stream>>>(S, T, 262144, 8, 1);
  // obj head + sigmoid, then NMS
  obj_sigmoid_kernel<<<64, 256, 0, stream>>>(T, w_obj, SC);
  nms_kernel<<<1, 64, 0, stream>>>(SC, out);
}

// Round 5
// 971.678 us; speedup vs baseline: 7.7614x; 1.1171x over previous
//
#include <hip/hip_runtime.h>
#include <hip/hip_bf16.h>

typedef float f4 __attribute__((ext_vector_type(4)));

// ---------------------------------------------------------------------------
// Stem: 512x512x3 --7x7 s2 pad2--> 256x256x64, ReLU.
// ---------------------------------------------------------------------------
__global__ __launch_bounds__(256) void stem_kernel(
    const float* __restrict__ in, const float* __restrict__ w,
    float* __restrict__ out)
{
  __shared__ float in_lds[37 * 37 * 3];   // 4107 floats
  __shared__ float w_lds[7 * 7 * 3 * 64]; // 9408 floats
  const int tid = threadIdx.x;
  const int ty0 = (blockIdx.x >> 4) * 16;
  const int tx0 = (blockIdx.x & 15) * 16;

  for (int idx = tid; idx < 9408; idx += 256) w_lds[idx] = w[idx];
  for (int idx = tid; idx < 4107; idx += 256) {
    int ci = idx % 3;
    int rem = idx / 3;
    int ix = rem % 37, iy = rem / 37;
    int gy = ty0 * 2 - 2 + iy, gx = tx0 * 2 - 2 + ix;
    float v = 0.f;
    if ((unsigned)gy < 512u && (unsigned)gx < 512u)
      v = in[(gy * 512 + gx) * 3 + ci];
    in_lds[idx] = v;
  }
  __syncthreads();

  const int co = (tid & 15) * 4;
  const int py = tid >> 4;
  f4 acc[16];
#pragma unroll
  for (int px = 0; px < 16; ++px) acc[px] = (f4)0.f;

  for (int ky = 0; ky < 7; ++ky)
    for (int kx = 0; kx < 7; ++kx)
#pragma unroll
      for (int ci = 0; ci < 3; ++ci) {
        f4 wv = *(const f4*)&w_lds[(((ky * 7 + kx) * 3) + ci) * 64 + co];
        const float* ip = &in_lds[((2 * py + ky) * 37 + kx) * 3 + ci];
#pragma unroll
        for (int px = 0; px < 16; ++px) {
          float iv = ip[px * 6];
          acc[px] += iv * wv;
        }
      }

#pragma unroll
  for (int px = 0; px < 16; ++px) {
    int oy = ty0 + py, ox = tx0 + px;
    f4 o = acc[px];
#pragma unroll
    for (int c = 0; c < 4; ++c) o[c] = fmaxf(o[c], 0.f);
    *(f4*)&out[(oy * 256 + ox) * 64 + co] = o;
  }
}

// ---------------------------------------------------------------------------
// 3x3 implicit-GEMM conv, NHWC fp32. Block tile 128 pix x 128 co, 256 thr,
// 8x8 outputs/thread. LDS DOUBLE-BUFFER, single barrier per chunk:
//   iter c: issue global loads for chunk c+1 -> regs; FMA from buf[c&1];
//   (vmcnt drains here, hidden by the 4096-cyc FMA phase) write regs to
//   buf[(c+1)&1]; barrier.
// No cross-iteration register copies / conditional moves (R3 spill lesson).
// Final iteration re-loads a clamped valid chunk (discarded) to keep control
// flow uniform. B-frag cols tx*4 / 64+tx*4 (2-way bank aliasing = free).
// gridDim.z splits C_in into slices of ci_per_z (partials at z*npix*C_out).
// ---------------------------------------------------------------------------
__global__ __launch_bounds__(256, 2) void conv128(
    const float* __restrict__ in, const float* __restrict__ w,
    float* __restrict__ pout,
    int H_in, int W_in, int C_in, int wshift, int C_out,
    int stride, int pad, int ci_per_z, int npix, int relu)
{
  __shared__ __align__(16) float As[2][128][36];  // [buf][pix][ci] (+4 pad)
  __shared__ __align__(16) float Bs[2][32][128];  // [buf][ci][co]
  const int tid = threadIdx.x;
  const int pix_base = blockIdx.x * 128;
  const int co_base = blockIdx.y * 128;
  const int ci_z0 = blockIdx.z * ci_per_z;
  const int ci_end = ci_z0 + ci_per_z;
  const int wmask = (1 << wshift) - 1;

  const int tx = tid & 15, ty = tid >> 4;

  // A staging decode: 128x32 floats = 1024 f4, 4 per thread
  int a_pix[4], a_c4[4], a_ys[4], a_xs[4];
#pragma unroll
  for (int q = 0; q < 4; ++q) {
    int f = q * 256 + tid;
    a_pix[q] = f >> 3; a_c4[q] = f & 7;
    int p = pix_base + a_pix[q];
    a_ys[q] = (p >> wshift) * stride - pad;
    a_xs[q] = (p & wmask) * stride - pad;
  }
  // B staging decode: 32x128 floats = 1024 f4, 4 per thread
  int b_row[4], b_co4[4];
#pragma unroll
  for (int q = 0; q < 4; ++q) {
    int f = q * 256 + tid;
    b_row[q] = f >> 5; b_co4[q] = f & 31;
  }

  f4 acc0[8], acc1[8];
#pragma unroll
  for (int i = 0; i < 8; ++i) { acc0[i] = (f4)0.f; acc1[i] = (f4)0.f; }

  f4 ra[4], rb[4];

#define LOADCHUNK(KY, KX, CI)                                                  \
  do {                                                                         \
    _Pragma("unroll")                                                          \
    for (int q = 0; q < 4; ++q) {                                              \
      int iy = a_ys[q] + (KY);                                                 \
      int ix = a_xs[q] + (KX);                                                 \
      f4 av = (f4)0.f;                                                         \
      if (((unsigned)iy < (unsigned)H_in) && ((unsigned)ix < (unsigned)W_in))  \
        av = *(const f4*)(in + (size_t)(iy * W_in + ix) * C_in + (CI) +        \
                          a_c4[q] * 4);                                        \
      ra[q] = av;                                                              \
    }                                                                          \
    const float* bb = w + (size_t)(((KY) * 3 + (KX)) * C_in + (CI)) * C_out +  \
                      co_base;                                                 \
    _Pragma("unroll")                                                          \
    for (int q = 0; q < 4; ++q)                                                \
      rb[q] = *(const f4*)(bb + (size_t)b_row[q] * C_out + b_co4[q] * 4);      \
  } while (0)

  const int nc = ci_per_z >> 5;
  const int total = 9 * nc;

  // prologue: chunk 0 -> buf 0
  LOADCHUNK(0, 0, ci_z0);
#pragma unroll
  for (int q = 0; q < 4; ++q) *(f4*)&As[0][a_pix[q]][a_c4[q] * 4] = ra[q];
#pragma unroll
  for (int q = 0; q < 4; ++q) *(f4*)&Bs[0][b_row[q]][b_co4[q] * 4] = rb[q];
  __syncthreads();

  // chunk-index walk (uniform registers, no div)
  int nky = 0, nkx = 0, nci = ci_z0;  // indices of the *next* chunk to load

  for (int c = 0; c < total; ++c) {
    const int buf = c & 1;
    // advance to chunk c+1 (clamped to a valid re-read on the last iter)
    nci += 32;
    if (nci == ci_end) { nci = ci_z0; nkx++; if (nkx == 3) { nkx = 0; nky++; } }
    if (nky == 3) nky = 0;  // c+1==total: harmless re-load of chunk 0
    LOADCHUNK(nky, nkx, nci);

    // compute from buf
#pragma unroll
    for (int kk = 0; kk < 32; kk += 4) {
      f4 a[8];
#pragma unroll
      for (int i = 0; i < 8; ++i) a[i] = *(const f4*)&As[buf][ty * 8 + i][kk];
#pragma unroll
      for (int j = 0; j < 4; ++j) {
        f4 b0 = *(const f4*)&Bs[buf][kk + j][tx * 4];
        f4 b1 = *(const f4*)&Bs[buf][kk + j][64 + tx * 4];
#pragma unroll
        for (int i = 0; i < 8; ++i) {
          float av = a[i][j];
          acc0[i] += av * b0;
          acc1[i] += av * b1;
        }
      }
    }

    // store prefetched chunk to the other buffer
#pragma unroll
    for (int q = 0; q < 4; ++q) *(f4*)&As[buf ^ 1][a_pix[q]][a_c4[q] * 4] = ra[q];
#pragma unroll
    for (int q = 0; q < 4; ++q) *(f4*)&Bs[buf ^ 1][b_row[q]][b_co4[q] * 4] = rb[q];
    __syncthreads();
  }
#undef LOADCHUNK

  float* dst = pout + (size_t)blockIdx.z * npix * C_out;
#pragma unroll
  for (int i = 0; i < 8; ++i) {
    int p = pix_base + ty * 8 + i;
    f4 o0 = acc0[i], o1 = acc1[i];
    if (relu) {
#pragma unroll
      for (int c = 0; c < 4; ++c) { o0[c] = fmaxf(o0[c], 0.f); o1[c] = fmaxf(o1[c], 0.f); }
    }
    *(f4*)&dst[(size_t)p * C_out + co_base + tx * 4] = o0;
    *(f4*)&dst[(size_t)p * C_out + co_base + 64 + tx * 4] = o1;
  }
}

// ---------------------------------------------------------------------------
// Sum Z partial slices (f4-vectorized) + optional ReLU.
// ---------------------------------------------------------------------------
__global__ __launch_bounds__(256) void reduce_relu_kernel(
    const float* __restrict__ p, float* __restrict__ out, int n4, int Z, int relu)
{
  int idx = blockIdx.x * 256 + threadIdx.x;
  if (idx >= n4) return;
  const f4* pv = (const f4*)p;
  f4 s = pv[idx];
  for (int z = 1; z < Z; ++z) s += pv[(size_t)z * n4 + idx];
  if (relu) {
#pragma unroll
    for (int c = 0; c < 4; ++c) s[c] = fmaxf(s[c], 0.f);
  }
  ((f4*)out)[idx] = s;
}

// ---------------------------------------------------------------------------
// 1x1-conv GEMM tile: 64 pix x 64 co, 256 thr, 4 pix x 4 co per thread.
// ---------------------------------------------------------------------------
__global__ __launch_bounds__(256) void gemm64(
    const float* __restrict__ in, const float* __restrict__ w,
    float* __restrict__ pout, int C_in, int C_out, int ci_per_z, int npix)
{
  __shared__ __align__(16) float As2[32][68];
  __shared__ __align__(16) float Bs[32][64];
  const int tid = threadIdx.x;
  const int pix_base = blockIdx.x * 64;
  const int co_base = blockIdx.y * 64;
  const int ci_z0 = blockIdx.z * ci_per_z;
  const int tx = tid & 15, ty = tid >> 4;

  int ga_pix[2], ga_c4[2];
#pragma unroll
  for (int q = 0; q < 2; ++q) {
    int f = q * 256 + tid;
    ga_pix[q] = f >> 3; ga_c4[q] = f & 7;
  }
  int gb_row[2], gb_c4[2];
#pragma unroll
  for (int q = 0; q < 2; ++q) {
    int f = q * 256 + tid;
    gb_row[q] = f >> 4; gb_c4[q] = f & 15;
  }

  f4 acc[4];
#pragma unroll
  for (int i = 0; i < 4; ++i) acc[i] = (f4)0.f;

  for (int ci = ci_z0; ci < ci_z0 + ci_per_z; ci += 32) {
    __syncthreads();
#pragma unroll
    for (int q = 0; q < 2; ++q) {
      f4 av = *(const f4*)&in[(size_t)(pix_base + ga_pix[q]) * C_in + ci + ga_c4[q] * 4];
#pragma unroll
      for (int u = 0; u < 4; ++u) As2[ga_c4[q] * 4 + u][ga_pix[q]] = av[u];
    }
#pragma unroll
    for (int q = 0; q < 2; ++q) {
      *(f4*)&Bs[gb_row[q]][gb_c4[q] * 4] =
          *(const f4*)&w[(size_t)(ci + gb_row[q]) * C_out + co_base + gb_c4[q] * 4];
    }
    __syncthreads();
#pragma unroll
    for (int kk = 0; kk < 32; ++kk) {
      f4 a = *(const f4*)&As2[kk][ty * 4];
      f4 b = *(const f4*)&Bs[kk][tx * 4];
#pragma unroll
      for (int i = 0; i < 4; ++i) acc[i] += a[i] * b;
    }
  }

  float* dst = pout + (size_t)blockIdx.z * npix * C_out;
#pragma unroll
  for (int i = 0; i < 4; ++i)
    *(f4*)&dst[(size_t)(pix_base + ty * 4 + i) * C_out + co_base + tx * 4] = acc[i];
}

// ---------------------------------------------------------------------------
// Sum Z partial slices + optional fused nearest-up2 residual (C_out=256).
// ---------------------------------------------------------------------------
__global__ __launch_bounds__(256) void reduce_up2_kernel(
    const float* __restrict__ p, const float* __restrict__ res,
    float* __restrict__ out, int n4, int Z, int wshift)
{
  int idx = blockIdx.x * 256 + threadIdx.x;
  if (idx >= n4) return;
  const f4* pv = (const f4*)p;
  f4 s = pv[idx];
  for (int z = 1; z < Z; ++z) s += pv[(size_t)z * n4 + idx];
  if (res) {
    int pix = idx >> 6, c4 = idx & 63;
    int oy = pix >> wshift, ox = pix & ((1 << wshift) - 1);
    int rp = ((oy >> 1) << (wshift - 1)) + (ox >> 1);
    s += ((const f4*)res)[rp * 64 + c4];
  }
  ((f4*)out)[idx] = s;
}

// ---------------------------------------------------------------------------
// obj head (1x1, 256->1) + sigmoid. 4 threads/pixel, quad shuffle-reduce.
// ---------------------------------------------------------------------------
__global__ __launch_bounds__(256) void obj_sigmoid_kernel(
    const float* __restrict__ t, const float* __restrict__ wobj,
    float* __restrict__ scores)
{
  __shared__ float wl[256];
  const int tid = threadIdx.x;
  wl[tid] = wobj[tid];
  __syncthreads();
  const int pix = blockIdx.x * 64 + (tid >> 2);
  const int c0 = (tid & 3) * 64;
  float acc = 0.f;
#pragma unroll
  for (int k = 0; k < 16; ++k) {
    f4 tv = *(const f4*)&t[(size_t)pix * 256 + c0 + k * 4];
    const float* wp = &wl[c0 + k * 4];
    acc += tv[0] * wp[0] + tv[1] * wp[1] + tv[2] * wp[2] + tv[3] * wp[3];
  }
  acc += __shfl_xor(acc, 1);
  acc += __shfl_xor(acc, 2);
  if ((tid & 3) == 0) scores[pix] = 1.f / (1.f + expf(-acc));
}

// ---------------------------------------------------------------------------
// Greedy NMS, single wave, validated (kept identical).
// ---------------------------------------------------------------------------
__global__ __launch_bounds__(64) void nms_kernel(
    const float* __restrict__ scores, float* __restrict__ out)
{
  __shared__ __align__(16) float sw[64 * 68];
  const int lane = threadIdx.x;  // = row i
  const float inv63 = 1.0f / 63.0f;

#pragma unroll
  for (int r = 0; r < 64; ++r)
    sw[r * 68 + lane] = scores[r * 64 + lane];
  __syncthreads();

  float bv = -3.0e38f;
  int bj = 0;
  {
    const float* row = &sw[lane * 68];
#pragma unroll
    for (int jq = 0; jq < 16; ++jq) {
      f4 v4 = *(const f4*)&row[jq * 4];
#pragma unroll
      for (int c = 0; c < 4; ++c) {
        float v = v4[c];
        int j = jq * 4 + c;
        if (v > bv) { bv = v; bj = j; }
      }
    }
  }

  for (int it = 0; it < 100; ++it) {
    float v = bv;
    int k = (lane << 6) | bj;
#pragma unroll
    for (int off = 32; off > 0; off >>= 1) {
      float ov = __shfl_down(v, off);
      int ok = __shfl_down(k, off);
      if (ov > v || (ov == v && ok < k)) { v = ov; k = ok; }
    }
    v = __shfl(v, 0);
    k = __shfl(k, 0);

    const int si = k >> 6, sj = k & 63;
    const float ay = sj * inv63, ax = si * inv63;
    const float a0 = fmaxf(ay - 0.05f, 0.f);
    const float a1 = fmaxf(ax - 0.05f, 0.f);
    const float a2 = fminf(ay + 0.05f, 1.f);
    const float a3 = fminf(ax + 0.05f, 1.f);
    const float barea = (a2 - a0) * (a3 - a1);

    if (lane == 0) {
      bool valid = v > -5.0e29f;
      out[it * 4 + 0] = valid ? a0 : 0.f;
      out[it * 4 + 1] = valid ? a1 : 0.f;
      out[it * 4 + 2] = valid ? a2 : 0.f;
      out[it * 4 + 3] = valid ? a3 : 0.f;
      out[400 + it] = valid ? v : 0.f;
    }

#pragma unroll
    for (int pass = 0; pass < 3; ++pass) {
      int e = pass * 64 + lane;
      if (e < 169) {
        int i = si - 6 + e / 13;
        int j = sj - 6 + e % 13;
        if ((unsigned)i < 64u && (unsigned)j < 64u) {
          float cy = j * inv63, cx = i * inv63;
          float c0 = fmaxf(cy - 0.05f, 0.f), c1 = fmaxf(cx - 0.05f, 0.f);
          float c2 = fminf(cy + 0.05f, 1.f), c3 = fminf(cx + 0.05f, 1.f);
          float yy1 = fmaxf(a0, c0), xx1 = fmaxf(a1, c1);
          float yy2 = fminf(a2, c2), xx2 = fminf(a3, c3);
          float inter = fmaxf(yy2 - yy1, 0.f) * fmaxf(xx2 - xx1, 0.f);
          float carea = (c2 - c0) * (c3 - c1);
          float iou = inter / (barea + carea - inter + 1e-9f);
          if (iou > 0.5f) sw[i * 68 + j] = -1.0e30f;
        }
      }
    }
    __syncthreads();

    int d = lane - si;
    if (d < 0) d = -d;
    if (d <= 6) {
      const float* row = &sw[lane * 68];
      float nv = -3.0e38f;
      int nj = 0;
#pragma unroll
      for (int jq = 0; jq < 16; ++jq) {
        f4 v4 = *(const f4*)&row[jq * 4];
#pragma unroll
        for (int c = 0; c < 4; ++c) {
          float vv = v4[c];
          int j = jq * 4 + c;
          if (vv > nv) { nv = vv; nj = j; }
        }
      }
      bv = nv; bj = nj;
    }
  }
}

// ---------------------------------------------------------------------------
extern "C" void kernel_launch(void* const* d_in, const int* in_sizes, int n_in,
                              void* d_out, int out_size, void* d_ws, size_t ws_size,
                              hipStream_t stream) {
  const float* x      = (const float*)d_in[0];
  const float* w_stem = (const float*)d_in[1];
  const float* w_c2   = (const float*)d_in[2];
  const float* w_c3   = (const float*)d_in[3];
  const float* w_c4   = (const float*)d_in[4];
  const float* w_c5   = (const float*)d_in[5];
  const float* l3     = (const float*)d_in[6];
  const float* l4     = (const float*)d_in[7];
  const float* l5     = (const float*)d_in[8];
  const float* o3w    = (const float*)d_in[9];
  const float* w_rpn  = (const float*)d_in[12];
  const float* w_obj  = (const float*)d_in[13];
  float* out = (float*)d_out;
  float* ws = (float*)d_ws;

  float* S   = ws;              // 256*256*64   = 4194304 floats (scratch/partials)
  float* C2  = S   + 4194304;   // 128*128*256  = 4194304
  float* C3  = C2  + 4194304;   // 64*64*512    = 2097152
  float* C4  = C3  + 2097152;   // 32*32*1024   = 1048576
  float* C5  = C4  + 1048576;   // 16*16*2048   = 524288
  float* P5  = C5  + 524288;    // 16*16*256    = 65536
  float* P4  = P5  + 65536;     // 32*32*256    = 262144
  float* P3P = P4  + 262144;    // 64*64*256    = 1048576
  float* P3  = P3P + 1048576;   // 1048576
  float* T   = P3  + 1048576;   // 1048576
  float* SC  = T   + 1048576;   // 4096

  // backbone
  stem_kernel<<<256, 256, 0, stream>>>(x, w_stem, S);
  conv128<<<dim3(128, 2, 1), 256, 0, stream>>>(
      S, w_c2, C2, 256, 256, 64, 7, 256, 2, 0, 64, 16384, 1);
  conv128<<<dim3(32, 4, 2), 256, 0, stream>>>(
      C2, w_c3, S, 128, 128, 256, 6, 512, 2, 0, 128, 4096, 0);
  reduce_relu_kernel<<<2048, 256, 0, stream>>>(S, C3, 524288, 2, 1);
  conv128<<<dim3(8, 8, 8), 256, 0, stream>>>(
      C3, w_c4, S, 64, 64, 512, 5, 1024, 2, 0, 64, 1024, 0);
  reduce_relu_kernel<<<1024, 256, 0, stream>>>(S, C4, 262144, 8, 1);
  conv128<<<dim3(2, 16, 16), 256, 0, stream>>>(
      C4, w_c5, S, 32, 32, 1024, 4, 2048, 2, 0, 64, 256, 0);
  reduce_relu_kernel<<<512, 256, 0, stream>>>(S, C5, 131072, 16, 1);
  // FPN laterals: gemm64 + Z-reduce with fused up2 add
  gemm64<<<dim3(4, 4, 8), 256, 0, stream>>>(C5, l5, S, 2048, 256, 256, 256);
  reduce_up2_kernel<<<64, 256, 0, stream>>>(S, nullptr, P5, 16384, 8, 4);
  gemm64<<<dim3(16, 4, 4), 256, 0, stream>>>(C4, l4, S, 1024, 256, 256, 1024);
  reduce_up2_kernel<<<256, 256, 0, stream>>>(S, P5, P4, 65536, 4, 5);
  gemm64<<<dim3(64, 4, 2), 256, 0, stream>>>(C3, l3, S, 512, 256, 256, 4096);
  reduce_up2_kernel<<<1024, 256, 0, stream>>>(S, P4, P3P, 262144, 2, 6);
  // o3 conv (no relu)
  conv128<<<dim3(32, 2, 8), 256, 0, stream>>>(
      P3P, o3w, S, 64, 64, 256, 6, 256, 1, 1, 32, 4096, 0);
  reduce_relu_kernel<<<1024, 256, 0, stream>>>(S, P3, 262144, 8, 0);
  // rpn shared conv (relu)
  conv128<<<dim3(32, 2, 8), 256, 0, stream>>>(
      P3, w_rpn, S, 64, 64, 256, 6, 256, 1, 1, 32, 4096, 0);
  reduce_relu_kernel<<<1024, 256, 0, stream>>>(S, T, 262144, 8, 1);
  // obj head + sigmoid, then NMS
  obj_sigmoid_kernel<<<64, 256, 0, stream>>>(T, w_obj, SC);
  nms_kernel<<<1, 64, 0, stream>>>(SC, out);
}

// Round 6
// 844.318 us; speedup vs baseline: 8.9322x; 1.1508x over previous
//
#include <hip/hip_runtime.h>
#include <hip/hip_bf16.h>

typedef float f4 __attribute__((ext_vector_type(4)));
typedef short s8v __attribute__((ext_vector_type(8)));      // 8 bf16 (MFMA frag)
typedef unsigned short us4 __attribute__((ext_vector_type(4)));
typedef unsigned short us8 __attribute__((ext_vector_type(8)));

// ---------------------------------------------------------------------------
// Stem: 512x512x3 --7x7 s2 pad2--> 256x256x64, ReLU. (fp32, small)
// ---------------------------------------------------------------------------
__global__ __launch_bounds__(256) void stem_kernel(
    const float* __restrict__ in, const float* __restrict__ w,
    float* __restrict__ out)
{
  __shared__ float in_lds[37 * 37 * 3];
  __shared__ float w_lds[7 * 7 * 3 * 64];
  const int tid = threadIdx.x;
  const int ty0 = (blockIdx.x >> 4) * 16;
  const int tx0 = (blockIdx.x & 15) * 16;

  for (int idx = tid; idx < 9408; idx += 256) w_lds[idx] = w[idx];
  for (int idx = tid; idx < 4107; idx += 256) {
    int ci = idx % 3;
    int rem = idx / 3;
    int ix = rem % 37, iy = rem / 37;
    int gy = ty0 * 2 - 2 + iy, gx = tx0 * 2 - 2 + ix;
    float v = 0.f;
    if ((unsigned)gy < 512u && (unsigned)gx < 512u)
      v = in[(gy * 512 + gx) * 3 + ci];
    in_lds[idx] = v;
  }
  __syncthreads();

  const int co = (tid & 15) * 4;
  const int py = tid >> 4;
  f4 acc[16];
#pragma unroll
  for (int px = 0; px < 16; ++px) acc[px] = (f4)0.f;

  for (int ky = 0; ky < 7; ++ky)
    for (int kx = 0; kx < 7; ++kx)
#pragma unroll
      for (int ci = 0; ci < 3; ++ci) {
        f4 wv = *(const f4*)&w_lds[(((ky * 7 + kx) * 3) + ci) * 64 + co];
        const float* ip = &in_lds[((2 * py + ky) * 37 + kx) * 3 + ci];
#pragma unroll
        for (int px = 0; px < 16; ++px) {
          float iv = ip[px * 6];
          acc[px] += iv * wv;
        }
      }

#pragma unroll
  for (int px = 0; px < 16; ++px) {
    int oy = ty0 + py, ox = tx0 + px;
    f4 o = acc[px];
#pragma unroll
    for (int c = 0; c < 4; ++c) o[c] = fmaxf(o[c], 0.f);
    *(f4*)&out[(oy * 256 + ox) * 64 + co] = o;
  }
}

// ---------------------------------------------------------------------------
// Weight prep: fp32 [tap][ci][co] -> 3-term bf16 split, TRANSPOSED to
// [L][tap][co][ci] (ushort). Truncation split: h=hi16(s), m=hi16(s-h),
// l=hi16(s-h-m); omitted residual ~2^-24|s| (fp32-noise level).
// grid (C_in/64, C_out/64, taps), 256 threads, LDS 64x64 transpose tile.
// ---------------------------------------------------------------------------
__global__ __launch_bounds__(256) void wsplit_kernel(
    const float* __restrict__ w, unsigned short* __restrict__ wt,
    int C_in, int C_out, int taps)
{
  __shared__ float t[64][68];
  const int tid = threadIdx.x;
  const int tap = blockIdx.z;
  const int ci0 = blockIdx.x * 64;
  const int co0 = blockIdx.y * 64;
  const size_t lstride = (size_t)taps * C_in * C_out;

#pragma unroll
  for (int q = 0; q < 4; ++q) {
    int f = q * 256 + tid;
    int r = f >> 4, c = f & 15;  // r = ci row, c = co f4-col
    f4 v = *(const f4*)&w[((size_t)(tap * C_in + ci0 + r)) * C_out + co0 + c * 4];
    *(f4*)&t[r][c * 4] = v;
  }
  __syncthreads();

#pragma unroll
  for (int q = 0; q < 4; ++q) {
    int f = q * 256 + tid;
    int r = f >> 4, c = f & 15;  // r = co row, c = ci f4-col
    us4 h, m, l;
#pragma unroll
    for (int u = 0; u < 4; ++u) {
      float s = t[c * 4 + u][r];
      unsigned int ub = __float_as_uint(s);
      unsigned short hh = (unsigned short)(ub >> 16);
      float r1 = s - __uint_as_float((unsigned int)hh << 16);
      unsigned short mm = (unsigned short)(__float_as_uint(r1) >> 16);
      float r2 = r1 - __uint_as_float((unsigned int)mm << 16);
      unsigned short ll = (unsigned short)(__float_as_uint(r2) >> 16);
      h[u] = hh; m[u] = mm; l[u] = ll;
    }
    size_t base = ((size_t)tap * C_out + co0 + r) * C_in + ci0 + c * 4;
    *(us4*)&wt[base] = h;
    *(us4*)&wt[lstride + base] = m;
    *(us4*)&wt[2 * lstride + base] = l;
  }
}

// ---------------------------------------------------------------------------
// 3x3 conv via MFMA (16x16x32 bf16) with exact 3-term split (6 products:
// hh, hm, mh, mm, hl, lh -> error at fp32-accumulation noise).
// Tile 128 pix x 128 co, 256 thr = 4 waves (2x2 of 64x64), chunk K=32.
// A (activations) fp32 from global, split in-kernel -> LDS [3][128][32] bf16.
// B (weights) pre-split/pre-transposed [L][tap][co][ci] -> straight b128 copy.
// Frag layouts (guide §3, m89/m91/m120): A[m=lane&15][k=(lane>>4)*8+j],
// B[k=(lane>>4)*8+j][n=lane&15], C col=lane&15 row=(lane>>4)*4+reg.
// gridDim.z splits C_in (partials at z*npix*C_out). relu only when Z==1.
// ---------------------------------------------------------------------------
__global__ __launch_bounds__(256, 2) void conv_mfma(
    const float* __restrict__ in, const unsigned short* __restrict__ wt,
    float* __restrict__ pout,
    int H_in, int W_in, int C_in, int wshift, int C_out,
    int stride, int pad, int ci_per_z, int npix, int relu)
{
  __shared__ __align__(16) unsigned short At[3][128][32];
  __shared__ __align__(16) unsigned short Bt[3][128][32];  // [L][co][k]
  const int tid = threadIdx.x;
  const int pix_base = blockIdx.x * 128;
  const int co_base = blockIdx.y * 128;
  const int ci_z0 = blockIdx.z * ci_per_z;
  const int wmask = (1 << wshift) - 1;
  const size_t lstride = (size_t)9 * C_in * C_out;

  const int lane = tid & 63, wv = tid >> 6;
  const int pixhalf = (wv >> 1) * 64, cohalf = (wv & 1) * 64;
  const int fm = lane & 15, fq = lane >> 4;

  // A staging decode: 128x32 fp32 = 1024 f4, 4 per thread
  int a_pix[4], a_c4[4], a_ys[4], a_xs[4];
#pragma unroll
  for (int q = 0; q < 4; ++q) {
    int f = q * 256 + tid;
    a_pix[q] = f >> 3; a_c4[q] = f & 7;
    int p = pix_base + a_pix[q];
    a_ys[q] = (p >> wshift) * stride - pad;
    a_xs[q] = (p & wmask) * stride - pad;
  }
  // B staging decode: per level 512 us8, 2 per thread
  int b_col[2], b_seg[2];
#pragma unroll
  for (int q = 0; q < 2; ++q) {
    int f = q * 256 + tid;
    b_col[q] = f >> 2; b_seg[q] = (f & 3) * 8;
  }

  f4 acc[4][4];
#pragma unroll
  for (int i = 0; i < 4; ++i)
#pragma unroll
    for (int j = 0; j < 4; ++j) acc[i][j] = (f4)0.f;

  for (int ky = 0; ky < 3; ++ky) {
    for (int kx = 0; kx < 3; ++kx) {
      const int tap = ky * 3 + kx;
      bool aval[4];
      const float* aptr[4];
#pragma unroll
      for (int q = 0; q < 4; ++q) {
        int iy = a_ys[q] + ky;
        int ix = a_xs[q] + kx;
        aval[q] = ((unsigned)iy < (unsigned)H_in) && ((unsigned)ix < (unsigned)W_in);
        aptr[q] = in + (size_t)(iy * W_in + ix) * C_in + a_c4[q] * 4;
      }
      const unsigned short* bbase =
          wt + (size_t)tap * C_out * C_in + (size_t)co_base * C_in;

      for (int ci = ci_z0; ci < ci_z0 + ci_per_z; ci += 32) {
        __syncthreads();  // previous compute done before LDS overwrite
        // ---- stage A: load fp32, 3-term split, write bf16 LDS ----
#pragma unroll
        for (int q = 0; q < 4; ++q) {
          f4 av = (f4)0.f;
          if (aval[q]) av = *(const f4*)(aptr[q] + ci);
          us4 h, m, l;
#pragma unroll
          for (int u = 0; u < 4; ++u) {
            float s = av[u];
            unsigned int ub = __float_as_uint(s);
            unsigned short hh = (unsigned short)(ub >> 16);
            float r1 = s - __uint_as_float((unsigned int)hh << 16);
            unsigned short mm = (unsigned short)(__float_as_uint(r1) >> 16);
            float r2 = r1 - __uint_as_float((unsigned int)mm << 16);
            unsigned short ll = (unsigned short)(__float_as_uint(r2) >> 16);
            h[u] = hh; m[u] = mm; l[u] = ll;
          }
          *(us4*)&At[0][a_pix[q]][a_c4[q] * 4] = h;
          *(us4*)&At[1][a_pix[q]][a_c4[q] * 4] = m;
          *(us4*)&At[2][a_pix[q]][a_c4[q] * 4] = l;
        }
        // ---- stage B: straight b128 copies of pre-split weights ----
#pragma unroll
        for (int L = 0; L < 3; ++L) {
#pragma unroll
          for (int q = 0; q < 2; ++q) {
            const unsigned short* src =
                bbase + L * lstride + (size_t)b_col[q] * C_in + ci + b_seg[q];
            *(us8*)&Bt[L][b_col[q]][b_seg[q]] = *(const us8*)src;
          }
        }
        __syncthreads();

        // ---- MFMA phase ----
        s8v Bh[4], Bm[4], Bl[4];
#pragma unroll
        for (int j = 0; j < 4; ++j) {
          Bh[j] = *(const s8v*)&Bt[0][cohalf + j * 16 + fm][fq * 8];
          Bm[j] = *(const s8v*)&Bt[1][cohalf + j * 16 + fm][fq * 8];
          Bl[j] = *(const s8v*)&Bt[2][cohalf + j * 16 + fm][fq * 8];
        }
        {
          s8v Ah[4];
#pragma unroll
          for (int i = 0; i < 4; ++i)
            Ah[i] = *(const s8v*)&At[0][pixhalf + i * 16 + fm][fq * 8];
#pragma unroll
          for (int i = 0; i < 4; ++i)
#pragma unroll
            for (int j = 0; j < 4; ++j) {
              acc[i][j] = __builtin_amdgcn_mfma_f32_16x16x32_bf16(Ah[i], Bh[j], acc[i][j], 0, 0, 0);
              acc[i][j] = __builtin_amdgcn_mfma_f32_16x16x32_bf16(Ah[i], Bm[j], acc[i][j], 0, 0, 0);
              acc[i][j] = __builtin_amdgcn_mfma_f32_16x16x32_bf16(Ah[i], Bl[j], acc[i][j], 0, 0, 0);
            }
        }
        {
          s8v Am[4];
#pragma unroll
          for (int i = 0; i < 4; ++i)
            Am[i] = *(const s8v*)&At[1][pixhalf + i * 16 + fm][fq * 8];
#pragma unroll
          for (int i = 0; i < 4; ++i)
#pragma unroll
            for (int j = 0; j < 4; ++j) {
              acc[i][j] = __builtin_amdgcn_mfma_f32_16x16x32_bf16(Am[i], Bh[j], acc[i][j], 0, 0, 0);
              acc[i][j] = __builtin_amdgcn_mfma_f32_16x16x32_bf16(Am[i], Bm[j], acc[i][j], 0, 0, 0);
            }
        }
        {
          s8v Al[4];
#pragma unroll
          for (int i = 0; i < 4; ++i)
            Al[i] = *(const s8v*)&At[2][pixhalf + i * 16 + fm][fq * 8];
#pragma unroll
          for (int i = 0; i < 4; ++i)
#pragma unroll
            for (int j = 0; j < 4; ++j)
              acc[i][j] = __builtin_amdgcn_mfma_f32_16x16x32_bf16(Al[i], Bh[j], acc[i][j], 0, 0, 0);
        }
      }
    }
  }

  float* dst = pout + (size_t)blockIdx.z * npix * C_out;
#pragma unroll
  for (int i = 0; i < 4; ++i) {
#pragma unroll
    for (int j = 0; j < 4; ++j) {
#pragma unroll
      for (int r = 0; r < 4; ++r) {
        int p = pix_base + pixhalf + i * 16 + fq * 4 + r;
        int co = co_base + cohalf + j * 16 + fm;
        float v = acc[i][j][r];
        if (relu) v = fmaxf(v, 0.f);
        dst[(size_t)p * C_out + co] = v;
      }
    }
  }
}

// ---------------------------------------------------------------------------
// Sum Z partial slices (f4-vectorized) + optional ReLU.
// ---------------------------------------------------------------------------
__global__ __launch_bounds__(256) void reduce_relu_kernel(
    const float* __restrict__ p, float* __restrict__ out, int n4, int Z, int relu)
{
  int idx = blockIdx.x * 256 + threadIdx.x;
  if (idx >= n4) return;
  const f4* pv = (const f4*)p;
  f4 s = pv[idx];
  for (int z = 1; z < Z; ++z) s += pv[(size_t)z * n4 + idx];
  if (relu) {
#pragma unroll
    for (int c = 0; c < 4; ++c) s[c] = fmaxf(s[c], 0.f);
  }
  ((f4*)out)[idx] = s;
}

// ---------------------------------------------------------------------------
// 1x1-conv GEMM tile: 64 pix x 64 co, 256 thr, 4 pix x 4 co per thread.
// ---------------------------------------------------------------------------
__global__ __launch_bounds__(256) void gemm64(
    const float* __restrict__ in, const float* __restrict__ w,
    float* __restrict__ pout, int C_in, int C_out, int ci_per_z, int npix)
{
  __shared__ __align__(16) float As2[32][68];
  __shared__ __align__(16) float Bs[32][64];
  const int tid = threadIdx.x;
  const int pix_base = blockIdx.x * 64;
  const int co_base = blockIdx.y * 64;
  const int ci_z0 = blockIdx.z * ci_per_z;
  const int tx = tid & 15, ty = tid >> 4;

  int ga_pix[2], ga_c4[2];
#pragma unroll
  for (int q = 0; q < 2; ++q) {
    int f = q * 256 + tid;
    ga_pix[q] = f >> 3; ga_c4[q] = f & 7;
  }
  int gb_row[2], gb_c4[2];
#pragma unroll
  for (int q = 0; q < 2; ++q) {
    int f = q * 256 + tid;
    gb_row[q] = f >> 4; gb_c4[q] = f & 15;
  }

  f4 acc[4];
#pragma unroll
  for (int i = 0; i < 4; ++i) acc[i] = (f4)0.f;

  for (int ci = ci_z0; ci < ci_z0 + ci_per_z; ci += 32) {
    __syncthreads();
#pragma unroll
    for (int q = 0; q < 2; ++q) {
      f4 av = *(const f4*)&in[(size_t)(pix_base + ga_pix[q]) * C_in + ci + ga_c4[q] * 4];
#pragma unroll
      for (int u = 0; u < 4; ++u) As2[ga_c4[q] * 4 + u][ga_pix[q]] = av[u];
    }
#pragma unroll
    for (int q = 0; q < 2; ++q) {
      *(f4*)&Bs[gb_row[q]][gb_c4[q] * 4] =
          *(const f4*)&w[(size_t)(ci + gb_row[q]) * C_out + co_base + gb_c4[q] * 4];
    }
    __syncthreads();
#pragma unroll
    for (int kk = 0; kk < 32; ++kk) {
      f4 a = *(const f4*)&As2[kk][ty * 4];
      f4 b = *(const f4*)&Bs[kk][tx * 4];
#pragma unroll
      for (int i = 0; i < 4; ++i) acc[i] += a[i] * b;
    }
  }

  float* dst = pout + (size_t)blockIdx.z * npix * C_out;
#pragma unroll
  for (int i = 0; i < 4; ++i)
    *(f4*)&dst[(size_t)(pix_base + ty * 4 + i) * C_out + co_base + tx * 4] = acc[i];
}

// ---------------------------------------------------------------------------
// Sum Z partial slices + optional fused nearest-up2 residual (C_out=256).
// ---------------------------------------------------------------------------
__global__ __launch_bounds__(256) void reduce_up2_kernel(
    const float* __restrict__ p, const float* __restrict__ res,
    float* __restrict__ out, int n4, int Z, int wshift)
{
  int idx = blockIdx.x * 256 + threadIdx.x;
  if (idx >= n4) return;
  const f4* pv = (const f4*)p;
  f4 s = pv[idx];
  for (int z = 1; z < Z; ++z) s += pv[(size_t)z * n4 + idx];
  if (res) {
    int pix = idx >> 6, c4 = idx & 63;
    int oy = pix >> wshift, ox = pix & ((1 << wshift) - 1);
    int rp = ((oy >> 1) << (wshift - 1)) + (ox >> 1);
    s += ((const f4*)res)[rp * 64 + c4];
  }
  ((f4*)out)[idx] = s;
}

// ---------------------------------------------------------------------------
// obj head (1x1, 256->1) + sigmoid. 4 threads/pixel, quad shuffle-reduce.
// ---------------------------------------------------------------------------
__global__ __launch_bounds__(256) void obj_sigmoid_kernel(
    const float* __restrict__ t, const float* __restrict__ wobj,
    float* __restrict__ scores)
{
  __shared__ float wl[256];
  const int tid = threadIdx.x;
  wl[tid] = wobj[tid];
  __syncthreads();
  const int pix = blockIdx.x * 64 + (tid >> 2);
  const int c0 = (tid & 3) * 64;
  float acc = 0.f;
#pragma unroll
  for (int k = 0; k < 16; ++k) {
    f4 tv = *(const f4*)&t[(size_t)pix * 256 + c0 + k * 4];
    const float* wp = &wl[c0 + k * 4];
    acc += tv[0] * wp[0] + tv[1] * wp[1] + tv[2] * wp[2] + tv[3] * wp[3];
  }
  acc += __shfl_xor(acc, 1);
  acc += __shfl_xor(acc, 2);
  if ((tid & 3) == 0) scores[pix] = 1.f / (1.f + expf(-acc));
}

// ---------------------------------------------------------------------------
// Greedy NMS, single wave, validated (kept identical).
// ---------------------------------------------------------------------------
__global__ __launch_bounds__(64) void nms_kernel(
    const float* __restrict__ scores, float* __restrict__ out)
{
  __shared__ __align__(16) float sw[64 * 68];
  const int lane = threadIdx.x;  // = row i
  const float inv63 = 1.0f / 63.0f;

#pragma unroll
  for (int r = 0; r < 64; ++r)
    sw[r * 68 + lane] = scores[r * 64 + lane];
  __syncthreads();

  float bv = -3.0e38f;
  int bj = 0;
  {
    const float* row = &sw[lane * 68];
#pragma unroll
    for (int jq = 0; jq < 16; ++jq) {
      f4 v4 = *(const f4*)&row[jq * 4];
#pragma unroll
      for (int c = 0; c < 4; ++c) {
        float v = v4[c];
        int j = jq * 4 + c;
        if (v > bv) { bv = v; bj = j; }
      }
    }
  }

  for (int it = 0; it < 100; ++it) {
    float v = bv;
    int k = (lane << 6) | bj;
#pragma unroll
    for (int off = 32; off > 0; off >>= 1) {
      float ov = __shfl_down(v, off);
      int ok = __shfl_down(k, off);
      if (ov > v || (ov == v && ok < k)) { v = ov; k = ok; }
    }
    v = __shfl(v, 0);
    k = __shfl(k, 0);

    const int si = k >> 6, sj = k & 63;
    const float ay = sj * inv63, ax = si * inv63;
    const float a0 = fmaxf(ay - 0.05f, 0.f);
    const float a1 = fmaxf(ax - 0.05f, 0.f);
    const float a2 = fminf(ay + 0.05f, 1.f);
    const float a3 = fminf(ax + 0.05f, 1.f);
    const float barea = (a2 - a0) * (a3 - a1);

    if (lane == 0) {
      bool valid = v > -5.0e29f;
      out[it * 4 + 0] = valid ? a0 : 0.f;
      out[it * 4 + 1] = valid ? a1 : 0.f;
      out[it * 4 + 2] = valid ? a2 : 0.f;
      out[it * 4 + 3] = valid ? a3 : 0.f;
      out[400 + it] = valid ? v : 0.f;
    }

#pragma unroll
    for (int pass = 0; pass < 3; ++pass) {
      int e = pass * 64 + lane;
      if (e < 169) {
        int i = si - 6 + e / 13;
        int j = sj - 6 + e % 13;
        if ((unsigned)i < 64u && (unsigned)j < 64u) {
          float cy = j * inv63, cx = i * inv63;
          float c0 = fmaxf(cy - 0.05f, 0.f), c1 = fmaxf(cx - 0.05f, 0.f);
          float c2 = fminf(cy + 0.05f, 1.f), c3 = fminf(cx + 0.05f, 1.f);
          float yy1 = fmaxf(a0, c0), xx1 = fmaxf(a1, c1);
          float yy2 = fminf(a2, c2), xx2 = fminf(a3, c3);
          float inter = fmaxf(yy2 - yy1, 0.f) * fmaxf(xx2 - xx1, 0.f);
          float carea = (c2 - c0) * (c3 - c1);
          float iou = inter / (barea + carea - inter + 1e-9f);
          if (iou > 0.5f) sw[i * 68 + j] = -1.0e30f;
        }
      }
    }
    __syncthreads();

    int d = lane - si;
    if (d < 0) d = -d;
    if (d <= 6) {
      const float* row = &sw[lane * 68];
      float nv = -3.0e38f;
      int nj = 0;
#pragma unroll
      for (int jq = 0; jq < 16; ++jq) {
        f4 v4 = *(const f4*)&row[jq * 4];
#pragma unroll
        for (int c = 0; c < 4; ++c) {
          float vv = v4[c];
          int j = jq * 4 + c;
          if (vv > nv) { nv = vv; nj = j; }
        }
      }
      bv = nv; bj = nj;
    }
  }
}

// ---------------------------------------------------------------------------
extern "C" void kernel_launch(void* const* d_in, const int* in_sizes, int n_in,
                              void* d_out, int out_size, void* d_ws, size_t ws_size,
                              hipStream_t stream) {
  const float* x      = (const float*)d_in[0];
  const float* w_stem = (const float*)d_in[1];
  const float* w_c2   = (const float*)d_in[2];
  const float* w_c3   = (const float*)d_in[3];
  const float* w_c4   = (const float*)d_in[4];
  const float* w_c5   = (const float*)d_in[5];
  const float* l3     = (const float*)d_in[6];
  const float* l4     = (const float*)d_in[7];
  const float* l5     = (const float*)d_in[8];
  const float* o3w    = (const float*)d_in[9];
  const float* w_rpn  = (const float*)d_in[12];
  const float* w_obj  = (const float*)d_in[13];
  float* out = (float*)d_out;
  float* ws = (float*)d_ws;

  float* S   = ws;              // 4,194,304 floats (partial-sum scratch)
  float* C2  = S   + 4194304;   // 4,194,304
  float* C3  = C2  + 4194304;   // 2,097,152
  float* C4  = C3  + 2097152;   // 1,048,576
  float* C5  = C4  + 1048576;   //   524,288
  float* P5  = C5  + 524288;    //    65,536
  float* P4  = P5  + 65536;     //   262,144
  float* P3P = P4  + 262144;    // 1,048,576
  float* P3  = P3P + 1048576;   // 1,048,576
  float* T   = P3  + 1048576;   // 1,048,576
  float* SC  = T   + 1048576;   //     4,096
  // Weight-split scratch (shared across convs, sized for c5):
  // 3 levels x 9 taps x 2048 co x 1024 ci ushorts = 113.25 MB
  unsigned short* WT = (unsigned short*)(SC + 4096);

  // backbone
  stem_kernel<<<256, 256, 0, stream>>>(x, w_stem, S);

  wsplit_kernel<<<dim3(1, 4, 9), 256, 0, stream>>>(w_c2, WT, 64, 256, 9);
  conv_mfma<<<dim3(128, 2, 1), 256, 0, stream>>>(
      S, WT, C2, 256, 256, 64, 7, 256, 2, 0, 64, 16384, 1);

  wsplit_kernel<<<dim3(4, 8, 9), 256, 0, stream>>>(w_c3, WT, 256, 512, 9);
  conv_mfma<<<dim3(32, 4, 2), 256, 0, stream>>>(
      C2, WT, S, 128, 128, 256, 6, 512, 2, 0, 128, 4096, 0);
  reduce_relu_kernel<<<2048, 256, 0, stream>>>(S, C3, 524288, 2, 1);

  wsplit_kernel<<<dim3(8, 16, 9), 256, 0, stream>>>(w_c4, WT, 512, 1024, 9);
  conv_mfma<<<dim3(8, 8, 8), 256, 0, stream>>>(
      C3, WT, S, 64, 64, 512, 5, 1024, 2, 0, 64, 1024, 0);
  reduce_relu_kernel<<<1024, 256, 0, stream>>>(S, C4, 262144, 8, 1);

  wsplit_kernel<<<dim3(16, 32, 9), 256, 0, stream>>>(w_c5, WT, 1024, 2048, 9);
  conv_mfma<<<dim3(2, 16, 16), 256, 0, stream>>>(
      C4, WT, S, 32, 32, 1024, 4, 2048, 2, 0, 64, 256, 0);
  reduce_relu_kernel<<<512, 256, 0, stream>>>(S, C5, 131072, 16, 1);

  // FPN laterals: gemm64 + Z-reduce with fused up2 add
  gemm64<<<dim3(4, 4, 8), 256, 0, stream>>>(C5, l5, S, 2048, 256, 256, 256);
  reduce_up2_kernel<<<64, 256, 0, stream>>>(S, nullptr, P5, 16384, 8, 4);
  gemm64<<<dim3(16, 4, 4), 256, 0, stream>>>(C4, l4, S, 1024, 256, 256, 1024);
  reduce_up2_kernel<<<256, 256, 0, stream>>>(S, P5, P4, 65536, 4, 5);
  gemm64<<<dim3(64, 4, 2), 256, 0, stream>>>(C3, l3, S, 512, 256, 256, 4096);
  reduce_up2_kernel<<<1024, 256, 0, stream>>>(S, P4, P3P, 262144, 2, 6);

  // o3 conv (no relu)
  wsplit_kernel<<<dim3(4, 4, 9), 256, 0, stream>>>(o3w, WT, 256, 256, 9);
  conv_mfma<<<dim3(32, 2, 8), 256, 0, stream>>>(
      P3P, WT, S, 64, 64, 256, 6, 256, 1, 1, 32, 4096, 0);
  reduce_relu_kernel<<<1024, 256, 0, stream>>>(S, P3, 262144, 8, 0);

  // rpn shared conv (relu)
  wsplit_kernel<<<dim3(4, 4, 9), 256, 0, stream>>>(w_rpn, WT, 256, 256, 9);
  conv_mfma<<<dim3(32, 2, 8), 256, 0, stream>>>(
      P3, WT, S, 64, 64, 256, 6, 256, 1, 1, 32, 4096, 0);
  reduce_relu_kernel<<<1024, 256, 0, stream>>>(S, T, 262144, 8, 1);

  // obj head + sigmoid, then NMS
  obj_sigmoid_kernel<<<64, 256, 0, stream>>>(T, w_obj, SC);
  nms_kernel<<<1, 64, 0, stream>>>(SC, out);
}

// Round 7
// 773.864 us; speedup vs baseline: 9.7454x; 1.0910x over previous
//
#include <hip/hip_runtime.h>
#include <hip/hip_bf16.h>

typedef float f4 __attribute__((ext_vector_type(4)));
typedef short s8v __attribute__((ext_vector_type(8)));      // 8 bf16 (MFMA frag)
typedef unsigned short us4 __attribute__((ext_vector_type(4)));
typedef unsigned short us8 __attribute__((ext_vector_type(8)));

// ---------------------------------------------------------------------------
// Stem: 512x512x3 --7x7 s2 pad2--> 256x256x64, ReLU. (fp32, small)
// ---------------------------------------------------------------------------
__global__ __launch_bounds__(256) void stem_kernel(
    const float* __restrict__ in, const float* __restrict__ w,
    float* __restrict__ out)
{
  __shared__ float in_lds[37 * 37 * 3];
  __shared__ float w_lds[7 * 7 * 3 * 64];
  const int tid = threadIdx.x;
  const int ty0 = (blockIdx.x >> 4) * 16;
  const int tx0 = (blockIdx.x & 15) * 16;

  for (int idx = tid; idx < 9408; idx += 256) w_lds[idx] = w[idx];
  for (int idx = tid; idx < 4107; idx += 256) {
    int ci = idx % 3;
    int rem = idx / 3;
    int ix = rem % 37, iy = rem / 37;
    int gy = ty0 * 2 - 2 + iy, gx = tx0 * 2 - 2 + ix;
    float v = 0.f;
    if ((unsigned)gy < 512u && (unsigned)gx < 512u)
      v = in[(gy * 512 + gx) * 3 + ci];
    in_lds[idx] = v;
  }
  __syncthreads();

  const int co = (tid & 15) * 4;
  const int py = tid >> 4;
  f4 acc[16];
#pragma unroll
  for (int px = 0; px < 16; ++px) acc[px] = (f4)0.f;

  for (int ky = 0; ky < 7; ++ky)
    for (int kx = 0; kx < 7; ++kx)
#pragma unroll
      for (int ci = 0; ci < 3; ++ci) {
        f4 wv = *(const f4*)&w_lds[(((ky * 7 + kx) * 3) + ci) * 64 + co];
        const float* ip = &in_lds[((2 * py + ky) * 37 + kx) * 3 + ci];
#pragma unroll
        for (int px = 0; px < 16; ++px) {
          float iv = ip[px * 6];
          acc[px] += iv * wv;
        }
      }

#pragma unroll
  for (int px = 0; px < 16; ++px) {
    int oy = ty0 + py, ox = tx0 + px;
    f4 o = acc[px];
#pragma unroll
    for (int c = 0; c < 4; ++c) o[c] = fmaxf(o[c], 0.f);
    *(f4*)&out[(oy * 256 + ox) * 64 + co] = o;
  }
}

// ---------------------------------------------------------------------------
// Weight prep: fp32 [tap][ci][co] -> 3-term bf16 split, TRANSPOSED to
// [L][tap][co][ci] (ushort).
// ---------------------------------------------------------------------------
__global__ __launch_bounds__(256) void wsplit_kernel(
    const float* __restrict__ w, unsigned short* __restrict__ wt,
    int C_in, int C_out, int taps)
{
  __shared__ float t[64][68];
  const int tid = threadIdx.x;
  const int tap = blockIdx.z;
  const int ci0 = blockIdx.x * 64;
  const int co0 = blockIdx.y * 64;
  const size_t lstride = (size_t)taps * C_in * C_out;

#pragma unroll
  for (int q = 0; q < 4; ++q) {
    int f = q * 256 + tid;
    int r = f >> 4, c = f & 15;  // r = ci row, c = co f4-col
    f4 v = *(const f4*)&w[((size_t)(tap * C_in + ci0 + r)) * C_out + co0 + c * 4];
    *(f4*)&t[r][c * 4] = v;
  }
  __syncthreads();

#pragma unroll
  for (int q = 0; q < 4; ++q) {
    int f = q * 256 + tid;
    int r = f >> 4, c = f & 15;  // r = co row, c = ci f4-col
    us4 h, m, l;
#pragma unroll
    for (int u = 0; u < 4; ++u) {
      float s = t[c * 4 + u][r];
      unsigned int ub = __float_as_uint(s);
      unsigned short hh = (unsigned short)(ub >> 16);
      float r1 = s - __uint_as_float((unsigned int)hh << 16);
      unsigned short mm = (unsigned short)(__float_as_uint(r1) >> 16);
      float r2 = r1 - __uint_as_float((unsigned int)mm << 16);
      unsigned short ll = (unsigned short)(__float_as_uint(r2) >> 16);
      h[u] = hh; m[u] = mm; l[u] = ll;
    }
    size_t base = ((size_t)tap * C_out + co0 + r) * C_in + ci0 + c * 4;
    *(us4*)&wt[base] = h;
    *(us4*)&wt[lstride + base] = m;
    *(us4*)&wt[2 * lstride + base] = l;
  }
}

// ---------------------------------------------------------------------------
// 3x3 conv via MFMA (16x16x32 bf16) with exact 3-term split (6 products).
// Validated R6 (absmax 0.0). Tile 128 pix x 128 co, 4 waves, chunk K=32.
// ---------------------------------------------------------------------------
__global__ __launch_bounds__(256, 2) void conv_mfma(
    const float* __restrict__ in, const unsigned short* __restrict__ wt,
    float* __restrict__ pout,
    int H_in, int W_in, int C_in, int wshift, int C_out,
    int stride, int pad, int ci_per_z, int npix, int relu)
{
  __shared__ __align__(16) unsigned short At[3][128][32];
  __shared__ __align__(16) unsigned short Bt[3][128][32];  // [L][co][k]
  const int tid = threadIdx.x;
  const int pix_base = blockIdx.x * 128;
  const int co_base = blockIdx.y * 128;
  const int ci_z0 = blockIdx.z * ci_per_z;
  const int wmask = (1 << wshift) - 1;
  const size_t lstride = (size_t)9 * C_in * C_out;

  const int lane = tid & 63, wv = tid >> 6;
  const int pixhalf = (wv >> 1) * 64, cohalf = (wv & 1) * 64;
  const int fm = lane & 15, fq = lane >> 4;

  int a_pix[4], a_c4[4], a_ys[4], a_xs[4];
#pragma unroll
  for (int q = 0; q < 4; ++q) {
    int f = q * 256 + tid;
    a_pix[q] = f >> 3; a_c4[q] = f & 7;
    int p = pix_base + a_pix[q];
    a_ys[q] = (p >> wshift) * stride - pad;
    a_xs[q] = (p & wmask) * stride - pad;
  }
  int b_col[2], b_seg[2];
#pragma unroll
  for (int q = 0; q < 2; ++q) {
    int f = q * 256 + tid;
    b_col[q] = f >> 2; b_seg[q] = (f & 3) * 8;
  }

  f4 acc[4][4];
#pragma unroll
  for (int i = 0; i < 4; ++i)
#pragma unroll
    for (int j = 0; j < 4; ++j) acc[i][j] = (f4)0.f;

  for (int ky = 0; ky < 3; ++ky) {
    for (int kx = 0; kx < 3; ++kx) {
      const int tap = ky * 3 + kx;
      bool aval[4];
      const float* aptr[4];
#pragma unroll
      for (int q = 0; q < 4; ++q) {
        int iy = a_ys[q] + ky;
        int ix = a_xs[q] + kx;
        aval[q] = ((unsigned)iy < (unsigned)H_in) && ((unsigned)ix < (unsigned)W_in);
        aptr[q] = in + (size_t)(iy * W_in + ix) * C_in + a_c4[q] * 4;
      }
      const unsigned short* bbase =
          wt + (size_t)tap * C_out * C_in + (size_t)co_base * C_in;

      for (int ci = ci_z0; ci < ci_z0 + ci_per_z; ci += 32) {
        __syncthreads();
#pragma unroll
        for (int q = 0; q < 4; ++q) {
          f4 av = (f4)0.f;
          if (aval[q]) av = *(const f4*)(aptr[q] + ci);
          us4 h, m, l;
#pragma unroll
          for (int u = 0; u < 4; ++u) {
            float s = av[u];
            unsigned int ub = __float_as_uint(s);
            unsigned short hh = (unsigned short)(ub >> 16);
            float r1 = s - __uint_as_float((unsigned int)hh << 16);
            unsigned short mm = (unsigned short)(__float_as_uint(r1) >> 16);
            float r2 = r1 - __uint_as_float((unsigned int)mm << 16);
            unsigned short ll = (unsigned short)(__float_as_uint(r2) >> 16);
            h[u] = hh; m[u] = mm; l[u] = ll;
          }
          *(us4*)&At[0][a_pix[q]][a_c4[q] * 4] = h;
          *(us4*)&At[1][a_pix[q]][a_c4[q] * 4] = m;
          *(us4*)&At[2][a_pix[q]][a_c4[q] * 4] = l;
        }
#pragma unroll
        for (int L = 0; L < 3; ++L) {
#pragma unroll
          for (int q = 0; q < 2; ++q) {
            const unsigned short* src =
                bbase + L * lstride + (size_t)b_col[q] * C_in + ci + b_seg[q];
            *(us8*)&Bt[L][b_col[q]][b_seg[q]] = *(const us8*)src;
          }
        }
        __syncthreads();

        s8v Bh[4], Bm[4], Bl[4];
#pragma unroll
        for (int j = 0; j < 4; ++j) {
          Bh[j] = *(const s8v*)&Bt[0][cohalf + j * 16 + fm][fq * 8];
          Bm[j] = *(const s8v*)&Bt[1][cohalf + j * 16 + fm][fq * 8];
          Bl[j] = *(const s8v*)&Bt[2][cohalf + j * 16 + fm][fq * 8];
        }
        {
          s8v Ah[4];
#pragma unroll
          for (int i = 0; i < 4; ++i)
            Ah[i] = *(const s8v*)&At[0][pixhalf + i * 16 + fm][fq * 8];
#pragma unroll
          for (int i = 0; i < 4; ++i)
#pragma unroll
            for (int j = 0; j < 4; ++j) {
              acc[i][j] = __builtin_amdgcn_mfma_f32_16x16x32_bf16(Ah[i], Bh[j], acc[i][j], 0, 0, 0);
              acc[i][j] = __builtin_amdgcn_mfma_f32_16x16x32_bf16(Ah[i], Bm[j], acc[i][j], 0, 0, 0);
              acc[i][j] = __builtin_amdgcn_mfma_f32_16x16x32_bf16(Ah[i], Bl[j], acc[i][j], 0, 0, 0);
            }
        }
        {
          s8v Am[4];
#pragma unroll
          for (int i = 0; i < 4; ++i)
            Am[i] = *(const s8v*)&At[1][pixhalf + i * 16 + fm][fq * 8];
#pragma unroll
          for (int i = 0; i < 4; ++i)
#pragma unroll
            for (int j = 0; j < 4; ++j) {
              acc[i][j] = __builtin_amdgcn_mfma_f32_16x16x32_bf16(Am[i], Bh[j], acc[i][j], 0, 0, 0);
              acc[i][j] = __builtin_amdgcn_mfma_f32_16x16x32_bf16(Am[i], Bm[j], acc[i][j], 0, 0, 0);
            }
        }
        {
          s8v Al[4];
#pragma unroll
          for (int i = 0; i < 4; ++i)
            Al[i] = *(const s8v*)&At[2][pixhalf + i * 16 + fm][fq * 8];
#pragma unroll
          for (int i = 0; i < 4; ++i)
#pragma unroll
            for (int j = 0; j < 4; ++j)
              acc[i][j] = __builtin_amdgcn_mfma_f32_16x16x32_bf16(Al[i], Bh[j], acc[i][j], 0, 0, 0);
        }
      }
    }
  }

  float* dst = pout + (size_t)blockIdx.z * npix * C_out;
#pragma unroll
  for (int i = 0; i < 4; ++i) {
#pragma unroll
    for (int j = 0; j < 4; ++j) {
#pragma unroll
      for (int r = 0; r < 4; ++r) {
        int p = pix_base + pixhalf + i * 16 + fq * 4 + r;
        int co = co_base + cohalf + j * 16 + fm;
        float v = acc[i][j][r];
        if (relu) v = fmaxf(v, 0.f);
        dst[(size_t)p * C_out + co] = v;
      }
    }
  }
}

// ---------------------------------------------------------------------------
// Sum Z partial slices (f4-vectorized) + optional ReLU.
// ---------------------------------------------------------------------------
__global__ __launch_bounds__(256) void reduce_relu_kernel(
    const float* __restrict__ p, float* __restrict__ out, int n4, int Z, int relu)
{
  int idx = blockIdx.x * 256 + threadIdx.x;
  if (idx >= n4) return;
  const f4* pv = (const f4*)p;
  f4 s = pv[idx];
  for (int z = 1; z < Z; ++z) s += pv[(size_t)z * n4 + idx];
  if (relu) {
#pragma unroll
    for (int c = 0; c < 4; ++c) s[c] = fmaxf(s[c], 0.f);
  }
  ((f4*)out)[idx] = s;
}

// ---------------------------------------------------------------------------
// 1x1-conv GEMM tile: 64 pix x 64 co, 256 thr, 4 pix x 4 co per thread.
// ---------------------------------------------------------------------------
__global__ __launch_bounds__(256) void gemm64(
    const float* __restrict__ in, const float* __restrict__ w,
    float* __restrict__ pout, int C_in, int C_out, int ci_per_z, int npix)
{
  __shared__ __align__(16) float As2[32][68];
  __shared__ __align__(16) float Bs[32][64];
  const int tid = threadIdx.x;
  const int pix_base = blockIdx.x * 64;
  const int co_base = blockIdx.y * 64;
  const int ci_z0 = blockIdx.z * ci_per_z;
  const int tx = tid & 15, ty = tid >> 4;

  int ga_pix[2], ga_c4[2];
#pragma unroll
  for (int q = 0; q < 2; ++q) {
    int f = q * 256 + tid;
    ga_pix[q] = f >> 3; ga_c4[q] = f & 7;
  }
  int gb_row[2], gb_c4[2];
#pragma unroll
  for (int q = 0; q < 2; ++q) {
    int f = q * 256 + tid;
    gb_row[q] = f >> 4; gb_c4[q] = f & 15;
  }

  f4 acc[4];
#pragma unroll
  for (int i = 0; i < 4; ++i) acc[i] = (f4)0.f;

  for (int ci = ci_z0; ci < ci_z0 + ci_per_z; ci += 32) {
    __syncthreads();
#pragma unroll
    for (int q = 0; q < 2; ++q) {
      f4 av = *(const f4*)&in[(size_t)(pix_base + ga_pix[q]) * C_in + ci + ga_c4[q] * 4];
#pragma unroll
      for (int u = 0; u < 4; ++u) As2[ga_c4[q] * 4 + u][ga_pix[q]] = av[u];
    }
#pragma unroll
    for (int q = 0; q < 2; ++q) {
      *(f4*)&Bs[gb_row[q]][gb_c4[q] * 4] =
          *(const f4*)&w[(size_t)(ci + gb_row[q]) * C_out + co_base + gb_c4[q] * 4];
    }
    __syncthreads();
#pragma unroll
    for (int kk = 0; kk < 32; ++kk) {
      f4 a = *(const f4*)&As2[kk][ty * 4];
      f4 b = *(const f4*)&Bs[kk][tx * 4];
#pragma unroll
      for (int i = 0; i < 4; ++i) acc[i] += a[i] * b;
    }
  }

  float* dst = pout + (size_t)blockIdx.z * npix * C_out;
#pragma unroll
  for (int i = 0; i < 4; ++i)
    *(f4*)&dst[(size_t)(pix_base + ty * 4 + i) * C_out + co_base + tx * 4] = acc[i];
}

// ---------------------------------------------------------------------------
// Sum Z partial slices + optional fused nearest-up2 residual (C_out=256).
// ---------------------------------------------------------------------------
__global__ __launch_bounds__(256) void reduce_up2_kernel(
    const float* __restrict__ p, const float* __restrict__ res,
    float* __restrict__ out, int n4, int Z, int wshift)
{
  int idx = blockIdx.x * 256 + threadIdx.x;
  if (idx >= n4) return;
  const f4* pv = (const f4*)p;
  f4 s = pv[idx];
  for (int z = 1; z < Z; ++z) s += pv[(size_t)z * n4 + idx];
  if (res) {
    int pix = idx >> 6, c4 = idx & 63;
    int oy = pix >> wshift, ox = pix & ((1 << wshift) - 1);
    int rp = ((oy >> 1) << (wshift - 1)) + (ox >> 1);
    s += ((const f4*)res)[rp * 64 + c4];
  }
  ((f4*)out)[idx] = s;
}

// ---------------------------------------------------------------------------
// obj head (1x1, 256->1) + sigmoid. 4 threads/pixel, quad shuffle-reduce.
// ---------------------------------------------------------------------------
__global__ __launch_bounds__(256) void obj_sigmoid_kernel(
    const float* __restrict__ t, const float* __restrict__ wobj,
    float* __restrict__ scores)
{
  __shared__ float wl[256];
  const int tid = threadIdx.x;
  wl[tid] = wobj[tid];
  __syncthreads();
  const int pix = blockIdx.x * 64 + (tid >> 2);
  const int c0 = (tid & 3) * 64;
  float acc = 0.f;
#pragma unroll
  for (int k = 0; k < 16; ++k) {
    f4 tv = *(const f4*)&t[(size_t)pix * 256 + c0 + k * 4];
    const float* wp = &wl[c0 + k * 4];
    acc += tv[0] * wp[0] + tv[1] * wp[1] + tv[2] * wp[2] + tv[3] * wp[3];
  }
  acc += __shfl_xor(acc, 1);
  acc += __shfl_xor(acc, 2);
  if ((tid & 3) == 0) scores[pix] = 1.f / (1.f + expf(-acc));
}

// ---------------------------------------------------------------------------
// NMS via sort + scan-accept (exact equivalence to greedy NMS):
// process boxes in descending score (stable: ties -> lower index, matching
// jnp.argmax); accept iff IoU<=0.5 vs all previously accepted. The running
// argmax of the suppress-and-rescan loop is exactly the next unsuppressed
// box in sorted order. Scores are sigmoid>0 => every accept is valid;
// outputs past the accept count are zeros (= reference's NEG picks).
// Phase 1: 256-thread bitonic sort of u64 keys ((0x40000000-bits)<<16 | idx).
// Phase 2: wave 0 only; 64 candidates/batch; each lane tests its candidate
// vs the accepted list in LDS (parallel over lanes), then intra-batch
// resolution via ballot/ctz + shuffle-broadcast IoU. IoU math byte-identical
// to the validated R3-R6 kernel (division, +1e-9, border clipping).
// ---------------------------------------------------------------------------
__global__ __launch_bounds__(256) void nms_kernel(
    const float* __restrict__ scores, float* __restrict__ out)
{
  __shared__ unsigned long long keys[4096];  // 32 KB
  __shared__ float acc_lds[100 * 8];         // accepted: b0,b1,b2,b3,area
  const int tid = threadIdx.x;
  const float inv63 = 1.0f / 63.0f;

  // zero the 500-float output (poisoned 0xAA before every launch)
  if (tid < 125) ((f4*)out)[tid] = (f4)0.f;

  // build keys: ascending sort == descending score, ties -> ascending idx
#pragma unroll
  for (int r = 0; r < 16; ++r) {
    int idx = r * 256 + tid;
    unsigned int bits = __float_as_uint(scores[idx]);  // in [0, 0x3F800000]
    keys[idx] = ((unsigned long long)(0x40000000u - bits) << 16) |
                (unsigned long long)idx;
  }
  __syncthreads();

  // bitonic sort, 4096 elements, 2048 pairs = 8 per thread per stage
  for (int k = 2; k <= 4096; k <<= 1) {
    for (int j = k >> 1; j > 0; j >>= 1) {
#pragma unroll 2
      for (int q = 0; q < 8; ++q) {
        int p = q * 256 + tid;
        int i = ((p & ~(j - 1)) << 1) | (p & (j - 1));
        int partner = i | j;
        bool up = ((i & k) == 0);
        unsigned long long a = keys[i], b = keys[partner];
        if ((a > b) == up) { keys[i] = b; keys[partner] = a; }
      }
      __syncthreads();
    }
  }

  if (tid >= 64) return;  // accept phase: wave 0 only (no barriers below)
  const int lane = tid;

  int n = 0;
  for (int b = 0; b < 64 && n < 100; ++b) {
    unsigned long long kk = keys[b * 64 + lane];
    int idx = (int)(kk & 0xFFFF);
    float sc = __uint_as_float(0x40000000u - (unsigned int)(kk >> 16));
    int si = idx >> 6, sj = idx & 63;
    float y = sj * inv63, x = si * inv63;
    float c0 = fmaxf(y - 0.05f, 0.f), c1 = fmaxf(x - 0.05f, 0.f);
    float c2 = fminf(y + 0.05f, 1.f), c3 = fminf(x + 0.05f, 1.f);
    float carea = (c2 - c0) * (c3 - c1);

    // phase 1: test vs previously accepted (broadcast LDS reads)
    bool sup = false;
    for (int a = 0; a < n; ++a) {
      f4 ab = *(const f4*)&acc_lds[a * 8];
      float aarea = acc_lds[a * 8 + 4];
      float yy1 = fmaxf(ab[0], c0), xx1 = fmaxf(ab[1], c1);
      float yy2 = fminf(ab[2], c2), xx2 = fminf(ab[3], c3);
      float inter = fmaxf(yy2 - yy1, 0.f) * fmaxf(xx2 - xx1, 0.f);
      float iou = inter / (aarea + carea - inter + 1e-9f);
      sup = sup || (iou > 0.5f);
    }

    // phase 2: resolve within batch in sorted order
    unsigned long long m = __ballot(!sup);
    while (m != 0 && n < 100) {
      int u = __builtin_ctzll(m);
      float b0 = __shfl(c0, u), b1 = __shfl(c1, u);
      float b2 = __shfl(c2, u), b3 = __shfl(c3, u);
      float ba = __shfl(carea, u);
      if (lane == u) {
        acc_lds[n * 8 + 0] = c0; acc_lds[n * 8 + 1] = c1;
        acc_lds[n * 8 + 2] = c2; acc_lds[n * 8 + 3] = c3;
        acc_lds[n * 8 + 4] = carea;
        out[n * 4 + 0] = c0; out[n * 4 + 1] = c1;
        out[n * 4 + 2] = c2; out[n * 4 + 3] = c3;
        out[400 + n] = sc;
        sup = true;  // self-suppression (iou with self = 1 > 0.5)
      }
      n++;
      if (lane > u && !sup) {
        float yy1 = fmaxf(b0, c0), xx1 = fmaxf(b1, c1);
        float yy2 = fminf(b2, c2), xx2 = fminf(b3, c3);
        float inter = fmaxf(yy2 - yy1, 0.f) * fmaxf(xx2 - xx1, 0.f);
        float iou = inter / (ba + carea - inter + 1e-9f);
        if (iou > 0.5f) sup = true;
      }
      m = __ballot(!sup);
    }
    __threadfence_block();  // acc_lds writes visible before next batch reads
  }
}

// ---------------------------------------------------------------------------
extern "C" void kernel_launch(void* const* d_in, const int* in_sizes, int n_in,
                              void* d_out, int out_size, void* d_ws, size_t ws_size,
                              hipStream_t stream) {
  const float* x      = (const float*)d_in[0];
  const float* w_stem = (const float*)d_in[1];
  const float* w_c2   = (const float*)d_in[2];
  const float* w_c3   = (const float*)d_in[3];
  const float* w_c4   = (const float*)d_in[4];
  const float* w_c5   = (const float*)d_in[5];
  const float* l3     = (const float*)d_in[6];
  const float* l4     = (const float*)d_in[7];
  const float* l5     = (const float*)d_in[8];
  const float* o3w    = (const float*)d_in[9];
  const float* w_rpn  = (const float*)d_in[12];
  const float* w_obj  = (const float*)d_in[13];
  float* out = (float*)d_out;
  float* ws = (float*)d_ws;

  float* S   = ws;              // 4,194,304 floats (partial-sum scratch)
  float* C2  = S   + 4194304;   // 4,194,304
  float* C3  = C2  + 4194304;   // 2,097,152
  float* C4  = C3  + 2097152;   // 1,048,576
  float* C5  = C4  + 1048576;   //   524,288
  float* P5  = C5  + 524288;    //    65,536
  float* P4  = P5  + 65536;     //   262,144
  float* P3P = P4  + 262144;    // 1,048,576
  float* P3  = P3P + 1048576;   // 1,048,576
  float* T   = P3  + 1048576;   // 1,048,576
  float* SC  = T   + 1048576;   //     4,096
  unsigned short* WT = (unsigned short*)(SC + 4096);  // 113.25 MB weight split

  // backbone
  stem_kernel<<<256, 256, 0, stream>>>(x, w_stem, S);

  wsplit_kernel<<<dim3(1, 4, 9), 256, 0, stream>>>(w_c2, WT, 64, 256, 9);
  conv_mfma<<<dim3(128, 2, 1), 256, 0, stream>>>(
      S, WT, C2, 256, 256, 64, 7, 256, 2, 0, 64, 16384, 1);

  wsplit_kernel<<<dim3(4, 8, 9), 256, 0, stream>>>(w_c3, WT, 256, 512, 9);
  conv_mfma<<<dim3(32, 4, 2), 256, 0, stream>>>(
      C2, WT, S, 128, 128, 256, 6, 512, 2, 0, 128, 4096, 0);
  reduce_relu_kernel<<<2048, 256, 0, stream>>>(S, C3, 524288, 2, 1);

  wsplit_kernel<<<dim3(8, 16, 9), 256, 0, stream>>>(w_c4, WT, 512, 1024, 9);
  conv_mfma<<<dim3(8, 8, 8), 256, 0, stream>>>(
      C3, WT, S, 64, 64, 512, 5, 1024, 2, 0, 64, 1024, 0);
  reduce_relu_kernel<<<1024, 256, 0, stream>>>(S, C4, 262144, 8, 1);

  wsplit_kernel<<<dim3(16, 32, 9), 256, 0, stream>>>(w_c5, WT, 1024, 2048, 9);
  conv_mfma<<<dim3(2, 16, 16), 256, 0, stream>>>(
      C4, WT, S, 32, 32, 1024, 4, 2048, 2, 0, 64, 256, 0);
  reduce_relu_kernel<<<512, 256, 0, stream>>>(S, C5, 131072, 16, 1);

  // FPN laterals: gemm64 + Z-reduce with fused up2 add
  gemm64<<<dim3(4, 4, 8), 256, 0, stream>>>(C5, l5, S, 2048, 256, 256, 256);
  reduce_up2_kernel<<<64, 256, 0, stream>>>(S, nullptr, P5, 16384, 8, 4);
  gemm64<<<dim3(16, 4, 4), 256, 0, stream>>>(C4, l4, S, 1024, 256, 256, 1024);
  reduce_up2_kernel<<<256, 256, 0, stream>>>(S, P5, P4, 65536, 4, 5);
  gemm64<<<dim3(64, 4, 2), 256, 0, stream>>>(C3, l3, S, 512, 256, 256, 4096);
  reduce_up2_kernel<<<1024, 256, 0, stream>>>(S, P4, P3P, 262144, 2, 6);

  // o3 conv (no relu)
  wsplit_kernel<<<dim3(4, 4, 9), 256, 0, stream>>>(o3w, WT, 256, 256, 9);
  conv_mfma<<<dim3(32, 2, 8), 256, 0, stream>>>(
      P3P, WT, S, 64, 64, 256, 6, 256, 1, 1, 32, 4096, 0);
  reduce_relu_kernel<<<1024, 256, 0, stream>>>(S, P3, 262144, 8, 0);

  // rpn shared conv (relu)
  wsplit_kernel<<<dim3(4, 4, 9), 256, 0, stream>>>(w_rpn, WT, 256, 256, 9);
  conv_mfma<<<dim3(32, 2, 8), 256, 0, stream>>>(
      P3, WT, S, 64, 64, 256, 6, 256, 1, 1, 32, 4096, 0);
  reduce_relu_kernel<<<1024, 256, 0, stream>>>(S, T, 262144, 8, 1);

  // obj head + sigmoid, then NMS
  obj_sigmoid_kernel<<<64, 256, 0, stream>>>(T, w_obj, SC);
  nms_kernel<<<1, 256, 0, stream>>>(SC, out);
}

// Round 8
// 733.459 us; speedup vs baseline: 10.2823x; 1.0551x over previous
//
#include <hip/hip_runtime.h>
#include <hip/hip_bf16.h>

typedef float f4 __attribute__((ext_vector_type(4)));
typedef short s8v __attribute__((ext_vector_type(8)));      // 8 bf16 (MFMA frag)
typedef unsigned short us4 __attribute__((ext_vector_type(4)));
typedef unsigned short us8 __attribute__((ext_vector_type(8)));

#define AP 40  // LDS row pad: 40 ushorts = 80 B = 20 banks -> 2-way (free)

// ---------------------------------------------------------------------------
// Stem: 512x512x3 --7x7 s2 pad2--> 256x256x64, ReLU. (fp32, small)
// ---------------------------------------------------------------------------
__global__ __launch_bounds__(256) void stem_kernel(
    const float* __restrict__ in, const float* __restrict__ w,
    float* __restrict__ out)
{
  __shared__ float in_lds[37 * 37 * 3];
  __shared__ float w_lds[7 * 7 * 3 * 64];
  const int tid = threadIdx.x;
  const int ty0 = (blockIdx.x >> 4) * 16;
  const int tx0 = (blockIdx.x & 15) * 16;

  for (int idx = tid; idx < 9408; idx += 256) w_lds[idx] = w[idx];
  for (int idx = tid; idx < 4107; idx += 256) {
    int ci = idx % 3;
    int rem = idx / 3;
    int ix = rem % 37, iy = rem / 37;
    int gy = ty0 * 2 - 2 + iy, gx = tx0 * 2 - 2 + ix;
    float v = 0.f;
    if ((unsigned)gy < 512u && (unsigned)gx < 512u)
      v = in[(gy * 512 + gx) * 3 + ci];
    in_lds[idx] = v;
  }
  __syncthreads();

  const int co = (tid & 15) * 4;
  const int py = tid >> 4;
  f4 acc[16];
#pragma unroll
  for (int px = 0; px < 16; ++px) acc[px] = (f4)0.f;

  for (int ky = 0; ky < 7; ++ky)
    for (int kx = 0; kx < 7; ++kx)
#pragma unroll
      for (int ci = 0; ci < 3; ++ci) {
        f4 wv = *(const f4*)&w_lds[(((ky * 7 + kx) * 3) + ci) * 64 + co];
        const float* ip = &in_lds[((2 * py + ky) * 37 + kx) * 3 + ci];
#pragma unroll
        for (int px = 0; px < 16; ++px) {
          float iv = ip[px * 6];
          acc[px] += iv * wv;
        }
      }

#pragma unroll
  for (int px = 0; px < 16; ++px) {
    int oy = ty0 + py, ox = tx0 + px;
    f4 o = acc[px];
#pragma unroll
    for (int c = 0; c < 4; ++c) o[c] = fmaxf(o[c], 0.f);
    *(f4*)&out[(oy * 256 + ox) * 64 + co] = o;
  }
}

// ---------------------------------------------------------------------------
// Weight prep: fp32 [tap][ci][co] -> 3-term bf16 split, TRANSPOSED to
// [L][tap][co][ci] (ushort).
// ---------------------------------------------------------------------------
__global__ __launch_bounds__(256) void wsplit_kernel(
    const float* __restrict__ w, unsigned short* __restrict__ wt,
    int C_in, int C_out, int taps)
{
  __shared__ float t[64][68];
  const int tid = threadIdx.x;
  const int tap = blockIdx.z;
  const int ci0 = blockIdx.x * 64;
  const int co0 = blockIdx.y * 64;
  const size_t lstride = (size_t)taps * C_in * C_out;

#pragma unroll
  for (int q = 0; q < 4; ++q) {
    int f = q * 256 + tid;
    int r = f >> 4, c = f & 15;  // r = ci row, c = co f4-col
    f4 v = *(const f4*)&w[((size_t)(tap * C_in + ci0 + r)) * C_out + co0 + c * 4];
    *(f4*)&t[r][c * 4] = v;
  }
  __syncthreads();

#pragma unroll
  for (int q = 0; q < 4; ++q) {
    int f = q * 256 + tid;
    int r = f >> 4, c = f & 15;  // r = co row, c = ci f4-col
    us4 h, m, l;
#pragma unroll
    for (int u = 0; u < 4; ++u) {
      float s = t[c * 4 + u][r];
      unsigned int ub = __float_as_uint(s);
      unsigned short hh = (unsigned short)(ub >> 16);
      float r1 = s - __uint_as_float((unsigned int)hh << 16);
      unsigned short mm = (unsigned short)(__float_as_uint(r1) >> 16);
      float r2 = r1 - __uint_as_float((unsigned int)mm << 16);
      unsigned short ll = (unsigned short)(__float_as_uint(r2) >> 16);
      h[u] = hh; m[u] = mm; l[u] = ll;
    }
    size_t base = ((size_t)tap * C_out + co0 + r) * C_in + ci0 + c * 4;
    *(us4*)&wt[base] = h;
    *(us4*)&wt[lstride + base] = m;
    *(us4*)&wt[2 * lstride + base] = l;
  }
}

// ---------------------------------------------------------------------------
// 3x3 conv via MFMA (16x16x32 bf16) with exact 3-term split (6 products).
// Validated R6/R7 (absmax 0.0). Tile 128 pix x 128 co, 4 waves, chunk K=32.
// R8: LDS rows padded to AP=40 ushorts (80 B): fragment b128 reads now start
// at 8 distinct 4-bank groups covering all 32 banks, 2 lanes/group = free
// (was 64 B rows -> banks {0,16} only -> 8-way conflict, 3.5M cycles).
// ---------------------------------------------------------------------------
__global__ __launch_bounds__(256, 2) void conv_mfma(
    const float* __restrict__ in, const unsigned short* __restrict__ wt,
    float* __restrict__ pout,
    int H_in, int W_in, int C_in, int wshift, int C_out,
    int stride, int pad, int ci_per_z, int npix, int relu)
{
  __shared__ __align__(16) unsigned short At[3][128][AP];
  __shared__ __align__(16) unsigned short Bt[3][128][AP];  // [L][co][k]
  const int tid = threadIdx.x;
  const int pix_base = blockIdx.x * 128;
  const int co_base = blockIdx.y * 128;
  const int ci_z0 = blockIdx.z * ci_per_z;
  const int wmask = (1 << wshift) - 1;
  const size_t lstride = (size_t)9 * C_in * C_out;

  const int lane = tid & 63, wv = tid >> 6;
  const int pixhalf = (wv >> 1) * 64, cohalf = (wv & 1) * 64;
  const int fm = lane & 15, fq = lane >> 4;

  int a_pix[4], a_c4[4], a_ys[4], a_xs[4];
#pragma unroll
  for (int q = 0; q < 4; ++q) {
    int f = q * 256 + tid;
    a_pix[q] = f >> 3; a_c4[q] = f & 7;
    int p = pix_base + a_pix[q];
    a_ys[q] = (p >> wshift) * stride - pad;
    a_xs[q] = (p & wmask) * stride - pad;
  }
  int b_col[2], b_seg[2];
#pragma unroll
  for (int q = 0; q < 2; ++q) {
    int f = q * 256 + tid;
    b_col[q] = f >> 2; b_seg[q] = (f & 3) * 8;
  }

  f4 acc[4][4];
#pragma unroll
  for (int i = 0; i < 4; ++i)
#pragma unroll
    for (int j = 0; j < 4; ++j) acc[i][j] = (f4)0.f;

  for (int ky = 0; ky < 3; ++ky) {
    for (int kx = 0; kx < 3; ++kx) {
      const int tap = ky * 3 + kx;
      bool aval[4];
      const float* aptr[4];
#pragma unroll
      for (int q = 0; q < 4; ++q) {
        int iy = a_ys[q] + ky;
        int ix = a_xs[q] + kx;
        aval[q] = ((unsigned)iy < (unsigned)H_in) && ((unsigned)ix < (unsigned)W_in);
        aptr[q] = in + (size_t)(iy * W_in + ix) * C_in + a_c4[q] * 4;
      }
      const unsigned short* bbase =
          wt + (size_t)tap * C_out * C_in + (size_t)co_base * C_in;

      for (int ci = ci_z0; ci < ci_z0 + ci_per_z; ci += 32) {
        __syncthreads();
#pragma unroll
        for (int q = 0; q < 4; ++q) {
          f4 av = (f4)0.f;
          if (aval[q]) av = *(const f4*)(aptr[q] + ci);
          us4 h, m, l;
#pragma unroll
          for (int u = 0; u < 4; ++u) {
            float s = av[u];
            unsigned int ub = __float_as_uint(s);
            unsigned short hh = (unsigned short)(ub >> 16);
            float r1 = s - __uint_as_float((unsigned int)hh << 16);
            unsigned short mm = (unsigned short)(__float_as_uint(r1) >> 16);
            float r2 = r1 - __uint_as_float((unsigned int)mm << 16);
            unsigned short ll = (unsigned short)(__float_as_uint(r2) >> 16);
            h[u] = hh; m[u] = mm; l[u] = ll;
          }
          *(us4*)&At[0][a_pix[q]][a_c4[q] * 4] = h;
          *(us4*)&At[1][a_pix[q]][a_c4[q] * 4] = m;
          *(us4*)&At[2][a_pix[q]][a_c4[q] * 4] = l;
        }
#pragma unroll
        for (int L = 0; L < 3; ++L) {
#pragma unroll
          for (int q = 0; q < 2; ++q) {
            const unsigned short* src =
                bbase + L * lstride + (size_t)b_col[q] * C_in + ci + b_seg[q];
            *(us8*)&Bt[L][b_col[q]][b_seg[q]] = *(const us8*)src;
          }
        }
        __syncthreads();

        s8v Bh[4], Bm[4], Bl[4];
#pragma unroll
        for (int j = 0; j < 4; ++j) {
          Bh[j] = *(const s8v*)&Bt[0][cohalf + j * 16 + fm][fq * 8];
          Bm[j] = *(const s8v*)&Bt[1][cohalf + j * 16 + fm][fq * 8];
          Bl[j] = *(const s8v*)&Bt[2][cohalf + j * 16 + fm][fq * 8];
        }
        {
          s8v Ah[4];
#pragma unroll
          for (int i = 0; i < 4; ++i)
            Ah[i] = *(const s8v*)&At[0][pixhalf + i * 16 + fm][fq * 8];
#pragma unroll
          for (int i = 0; i < 4; ++i)
#pragma unroll
            for (int j = 0; j < 4; ++j) {
              acc[i][j] = __builtin_amdgcn_mfma_f32_16x16x32_bf16(Ah[i], Bh[j], acc[i][j], 0, 0, 0);
              acc[i][j] = __builtin_amdgcn_mfma_f32_16x16x32_bf16(Ah[i], Bm[j], acc[i][j], 0, 0, 0);
              acc[i][j] = __builtin_amdgcn_mfma_f32_16x16x32_bf16(Ah[i], Bl[j], acc[i][j], 0, 0, 0);
            }
        }
        {
          s8v Am[4];
#pragma unroll
          for (int i = 0; i < 4; ++i)
            Am[i] = *(const s8v*)&At[1][pixhalf + i * 16 + fm][fq * 8];
#pragma unroll
          for (int i = 0; i < 4; ++i)
#pragma unroll
            for (int j = 0; j < 4; ++j) {
              acc[i][j] = __builtin_amdgcn_mfma_f32_16x16x32_bf16(Am[i], Bh[j], acc[i][j], 0, 0, 0);
              acc[i][j] = __builtin_amdgcn_mfma_f32_16x16x32_bf16(Am[i], Bm[j], acc[i][j], 0, 0, 0);
            }
        }
        {
          s8v Al[4];
#pragma unroll
          for (int i = 0; i < 4; ++i)
            Al[i] = *(const s8v*)&At[2][pixhalf + i * 16 + fm][fq * 8];
#pragma unroll
          for (int i = 0; i < 4; ++i)
#pragma unroll
            for (int j = 0; j < 4; ++j)
              acc[i][j] = __builtin_amdgcn_mfma_f32_16x16x32_bf16(Al[i], Bh[j], acc[i][j], 0, 0, 0);
        }
      }
    }
  }

  float* dst = pout + (size_t)blockIdx.z * npix * C_out;
#pragma unroll
  for (int i = 0; i < 4; ++i) {
#pragma unroll
    for (int j = 0; j < 4; ++j) {
#pragma unroll
      for (int r = 0; r < 4; ++r) {
        int p = pix_base + pixhalf + i * 16 + fq * 4 + r;
        int co = co_base + cohalf + j * 16 + fm;
        float v = acc[i][j][r];
        if (relu) v = fmaxf(v, 0.f);
        dst[(size_t)p * C_out + co] = v;
      }
    }
  }
}

// ---------------------------------------------------------------------------
// Sum Z partial slices (f4-vectorized) + optional ReLU.
// ---------------------------------------------------------------------------
__global__ __launch_bounds__(256) void reduce_relu_kernel(
    const float* __restrict__ p, float* __restrict__ out, int n4, int Z, int relu)
{
  int idx = blockIdx.x * 256 + threadIdx.x;
  if (idx >= n4) return;
  const f4* pv = (const f4*)p;
  f4 s = pv[idx];
  for (int z = 1; z < Z; ++z) s += pv[(size_t)z * n4 + idx];
  if (relu) {
#pragma unroll
    for (int c = 0; c < 4; ++c) s[c] = fmaxf(s[c], 0.f);
  }
  ((f4*)out)[idx] = s;
}

// ---------------------------------------------------------------------------
// 1x1-conv GEMM tile: 64 pix x 64 co, 256 thr, 4 pix x 4 co per thread.
// ---------------------------------------------------------------------------
__global__ __launch_bounds__(256) void gemm64(
    const float* __restrict__ in, const float* __restrict__ w,
    float* __restrict__ pout, int C_in, int C_out, int ci_per_z, int npix)
{
  __shared__ __align__(16) float As2[32][68];
  __shared__ __align__(16) float Bs[32][64];
  const int tid = threadIdx.x;
  const int pix_base = blockIdx.x * 64;
  const int co_base = blockIdx.y * 64;
  const int ci_z0 = blockIdx.z * ci_per_z;
  const int tx = tid & 15, ty = tid >> 4;

  int ga_pix[2], ga_c4[2];
#pragma unroll
  for (int q = 0; q < 2; ++q) {
    int f = q * 256 + tid;
    ga_pix[q] = f >> 3; ga_c4[q] = f & 7;
  }
  int gb_row[2], gb_c4[2];
#pragma unroll
  for (int q = 0; q < 2; ++q) {
    int f = q * 256 + tid;
    gb_row[q] = f >> 4; gb_c4[q] = f & 15;
  }

  f4 acc[4];
#pragma unroll
  for (int i = 0; i < 4; ++i) acc[i] = (f4)0.f;

  for (int ci = ci_z0; ci < ci_z0 + ci_per_z; ci += 32) {
    __syncthreads();
#pragma unroll
    for (int q = 0; q < 2; ++q) {
      f4 av = *(const f4*)&in[(size_t)(pix_base + ga_pix[q]) * C_in + ci + ga_c4[q] * 4];
#pragma unroll
      for (int u = 0; u < 4; ++u) As2[ga_c4[q] * 4 + u][ga_pix[q]] = av[u];
    }
#pragma unroll
    for (int q = 0; q < 2; ++q) {
      *(f4*)&Bs[gb_row[q]][gb_c4[q] * 4] =
          *(const f4*)&w[(size_t)(ci + gb_row[q]) * C_out + co_base + gb_c4[q] * 4];
    }
    __syncthreads();
#pragma unroll
    for (int kk = 0; kk < 32; ++kk) {
      f4 a = *(const f4*)&As2[kk][ty * 4];
      f4 b = *(const f4*)&Bs[kk][tx * 4];
#pragma unroll
      for (int i = 0; i < 4; ++i) acc[i] += a[i] * b;
    }
  }

  float* dst = pout + (size_t)blockIdx.z * npix * C_out;
#pragma unroll
  for (int i = 0; i < 4; ++i)
    *(f4*)&dst[(size_t)(pix_base + ty * 4 + i) * C_out + co_base + tx * 4] = acc[i];
}

// ---------------------------------------------------------------------------
// Sum Z partial slices + optional fused nearest-up2 residual (C_out=256).
// ---------------------------------------------------------------------------
__global__ __launch_bounds__(256) void reduce_up2_kernel(
    const float* __restrict__ p, const float* __restrict__ res,
    float* __restrict__ out, int n4, int Z, int wshift)
{
  int idx = blockIdx.x * 256 + threadIdx.x;
  if (idx >= n4) return;
  const f4* pv = (const f4*)p;
  f4 s = pv[idx];
  for (int z = 1; z < Z; ++z) s += pv[(size_t)z * n4 + idx];
  if (res) {
    int pix = idx >> 6, c4 = idx & 63;
    int oy = pix >> wshift, ox = pix & ((1 << wshift) - 1);
    int rp = ((oy >> 1) << (wshift - 1)) + (ox >> 1);
    s += ((const f4*)res)[rp * 64 + c4];
  }
  ((f4*)out)[idx] = s;
}

// ---------------------------------------------------------------------------
// obj head (1x1, 256->1) + sigmoid. 4 threads/pixel, quad shuffle-reduce.
// ---------------------------------------------------------------------------
__global__ __launch_bounds__(256) void obj_sigmoid_kernel(
    const float* __restrict__ t, const float* __restrict__ wobj,
    float* __restrict__ scores)
{
  __shared__ float wl[256];
  const int tid = threadIdx.x;
  wl[tid] = wobj[tid];
  __syncthreads();
  const int pix = blockIdx.x * 64 + (tid >> 2);
  const int c0 = (tid & 3) * 64;
  float acc = 0.f;
#pragma unroll
  for (int k = 0; k < 16; ++k) {
    f4 tv = *(const f4*)&t[(size_t)pix * 256 + c0 + k * 4];
    const float* wp = &wl[c0 + k * 4];
    acc += tv[0] * wp[0] + tv[1] * wp[1] + tv[2] * wp[2] + tv[3] * wp[3];
  }
  acc += __shfl_xor(acc, 1);
  acc += __shfl_xor(acc, 2);
  if ((tid & 3) == 0) scores[pix] = 1.f / (1.f + expf(-acc));
}

// ---------------------------------------------------------------------------
// NMS via sort + scan-accept (validated R7, absmax 0.0). Kept identical.
// ---------------------------------------------------------------------------
__global__ __launch_bounds__(256) void nms_kernel(
    const float* __restrict__ scores, float* __restrict__ out)
{
  __shared__ unsigned long long keys[4096];  // 32 KB
  __shared__ float acc_lds[100 * 8];         // accepted: b0,b1,b2,b3,area
  const int tid = threadIdx.x;
  const float inv63 = 1.0f / 63.0f;

  if (tid < 125) ((f4*)out)[tid] = (f4)0.f;

#pragma unroll
  for (int r = 0; r < 16; ++r) {
    int idx = r * 256 + tid;
    unsigned int bits = __float_as_uint(scores[idx]);  // in [0, 0x3F800000]
    keys[idx] = ((unsigned long long)(0x40000000u - bits) << 16) |
                (unsigned long long)idx;
  }
  __syncthreads();

  for (int k = 2; k <= 4096; k <<= 1) {
    for (int j = k >> 1; j > 0; j >>= 1) {
#pragma unroll 2
      for (int q = 0; q < 8; ++q) {
        int p = q * 256 + tid;
        int i = ((p & ~(j - 1)) << 1) | (p & (j - 1));
        int partner = i | j;
        bool up = ((i & k) == 0);
        unsigned long long a = keys[i], b = keys[partner];
        if ((a > b) == up) { keys[i] = b; keys[partner] = a; }
      }
      __syncthreads();
    }
  }

  if (tid >= 64) return;
  const int lane = tid;

  int n = 0;
  for (int b = 0; b < 64 && n < 100; ++b) {
    unsigned long long kk = keys[b * 64 + lane];
    int idx = (int)(kk & 0xFFFF);
    float sc = __uint_as_float(0x40000000u - (unsigned int)(kk >> 16));
    int si = idx >> 6, sj = idx & 63;
    float y = sj * inv63, x = si * inv63;
    float c0 = fmaxf(y - 0.05f, 0.f), c1 = fmaxf(x - 0.05f, 0.f);
    float c2 = fminf(y + 0.05f, 1.f), c3 = fminf(x + 0.05f, 1.f);
    float carea = (c2 - c0) * (c3 - c1);

    bool sup = false;
    for (int a = 0; a < n; ++a) {
      f4 ab = *(const f4*)&acc_lds[a * 8];
      float aarea = acc_lds[a * 8 + 4];
      float yy1 = fmaxf(ab[0], c0), xx1 = fmaxf(ab[1], c1);
      float yy2 = fminf(ab[2], c2), xx2 = fminf(ab[3], c3);
      float inter = fmaxf(yy2 - yy1, 0.f) * fmaxf(xx2 - xx1, 0.f);
      float iou = inter / (aarea + carea - inter + 1e-9f);
      sup = sup || (iou > 0.5f);
    }

    unsigned long long m = __ballot(!sup);
    while (m != 0 && n < 100) {
      int u = __builtin_ctzll(m);
      float b0 = __shfl(c0, u), b1 = __shfl(c1, u);
      float b2 = __shfl(c2, u), b3 = __shfl(c3, u);
      float ba = __shfl(carea, u);
      if (lane == u) {
        acc_lds[n * 8 + 0] = c0; acc_lds[n * 8 + 1] = c1;
        acc_lds[n * 8 + 2] = c2; acc_lds[n * 8 + 3] = c3;
        acc_lds[n * 8 + 4] = carea;
        out[n * 4 + 0] = c0; out[n * 4 + 1] = c1;
        out[n * 4 + 2] = c2; out[n * 4 + 3] = c3;
        out[400 + n] = sc;
        sup = true;
      }
      n++;
      if (lane > u && !sup) {
        float yy1 = fmaxf(b0, c0), xx1 = fmaxf(b1, c1);
        float yy2 = fminf(b2, c2), xx2 = fminf(b3, c3);
        float inter = fmaxf(yy2 - yy1, 0.f) * fmaxf(xx2 - xx1, 0.f);
        float iou = inter / (ba + carea - inter + 1e-9f);
        if (iou > 0.5f) sup = true;
      }
      m = __ballot(!sup);
    }
    __threadfence_block();
  }
}

// ---------------------------------------------------------------------------
extern "C" void kernel_launch(void* const* d_in, const int* in_sizes, int n_in,
                              void* d_out, int out_size, void* d_ws, size_t ws_size,
                              hipStream_t stream) {
  const float* x      = (const float*)d_in[0];
  const float* w_stem = (const float*)d_in[1];
  const float* w_c2   = (const float*)d_in[2];
  const float* w_c3   = (const float*)d_in[3];
  const float* w_c4   = (const float*)d_in[4];
  const float* w_c5   = (const float*)d_in[5];
  const float* l3     = (const float*)d_in[6];
  const float* l4     = (const float*)d_in[7];
  const float* l5     = (const float*)d_in[8];
  const float* o3w    = (const float*)d_in[9];
  const float* w_rpn  = (const float*)d_in[12];
  const float* w_obj  = (const float*)d_in[13];
  float* out = (float*)d_out;
  float* ws = (float*)d_ws;

  float* S   = ws;              // 4,194,304 floats (partial scratch for c4/c5/o3/rpn)
  float* C2  = S   + 4194304;   // 4,194,304
  float* C3  = C2  + 4194304;   // 2,097,152
  float* C4  = C3  + 2097152;   // 1,048,576
  float* C5  = C4  + 1048576;   //   524,288
  float* P5  = C5  + 524288;    //    65,536
  float* P4  = P5  + 65536;     //   262,144
  float* P3P = P4  + 262144;    // 1,048,576
  float* P3  = P3P + 1048576;   // 1,048,576
  float* T   = P3  + 1048576;   // 1,048,576
  float* SC  = T   + 1048576;   //     4,096
  unsigned short* WT = (unsigned short*)(SC + 4096);  // 113.25 MB weight split
  // PZ: 33.5 MB partial scratch for c2/c3, carved at WT+60 MB. Safe: c2/c3
  // weight splits are 1.7/7.1 MB (< 60 MB); c4's 28.3 MB < 60 MB; c5's full
  // 113 MB rewrite happens only after c3 is consumed (stream-serial).
  float* PZ = (float*)(WT + 31457280);

  // backbone
  stem_kernel<<<256, 256, 0, stream>>>(x, w_stem, S);

  wsplit_kernel<<<dim3(1, 4, 9), 256, 0, stream>>>(w_c2, WT, 64, 256, 9);
  conv_mfma<<<dim3(128, 2, 2), 256, 0, stream>>>(   // Z=2: 512 blocks = 2/CU
      S, WT, PZ, 256, 256, 64, 7, 256, 2, 0, 32, 16384, 0);
  reduce_relu_kernel<<<4096, 256, 0, stream>>>(PZ, C2, 1048576, 2, 1);

  wsplit_kernel<<<dim3(4, 8, 9), 256, 0, stream>>>(w_c3, WT, 256, 512, 9);
  conv_mfma<<<dim3(32, 4, 4), 256, 0, stream>>>(    // Z=4: 512 blocks = 2/CU
      C2, WT, PZ, 128, 128, 256, 6, 512, 2, 0, 64, 4096, 0);
  reduce_relu_kernel<<<2048, 256, 0, stream>>>(PZ, C3, 524288, 4, 1);

  wsplit_kernel<<<dim3(8, 16, 9), 256, 0, stream>>>(w_c4, WT, 512, 1024, 9);
  conv_mfma<<<dim3(8, 8, 8), 256, 0, stream>>>(
      C3, WT, S, 64, 64, 512, 5, 1024, 2, 0, 64, 1024, 0);
  reduce_relu_kernel<<<1024, 256, 0, stream>>>(S, C4, 262144, 8, 1);

  wsplit_kernel<<<dim3(16, 32, 9), 256, 0, stream>>>(w_c5, WT, 1024, 2048, 9);
  conv_mfma<<<dim3(2, 16, 16), 256, 0, stream>>>(
      C4, WT, S, 32, 32, 1024, 4, 2048, 2, 0, 64, 256, 0);
  reduce_relu_kernel<<<512, 256, 0, stream>>>(S, C5, 131072, 16, 1);

  // FPN laterals: gemm64 + Z-reduce with fused up2 add
  gemm64<<<dim3(4, 4, 8), 256, 0, stream>>>(C5, l5, S, 2048, 256, 256, 256);
  reduce_up2_kernel<<<64, 256, 0, stream>>>(S, nullptr, P5, 16384, 8, 4);
  gemm64<<<dim3(16, 4, 4), 256, 0, stream>>>(C4, l4, S, 1024, 256, 256, 1024);
  reduce_up2_kernel<<<256, 256, 0, stream>>>(S, P5, P4, 65536, 4, 5);
  gemm64<<<dim3(64, 4, 2), 256, 0, stream>>>(C3, l3, S, 512, 256, 256, 4096);
  reduce_up2_kernel<<<1024, 256, 0, stream>>>(S, P4, P3P, 262144, 2, 6);

  // o3 conv (no relu)
  wsplit_kernel<<<dim3(4, 4, 9), 256, 0, stream>>>(o3w, WT, 256, 256, 9);
  conv_mfma<<<dim3(32, 2, 8), 256, 0, stream>>>(
      P3P, WT, S, 64, 64, 256, 6, 256, 1, 1, 32, 4096, 0);
  reduce_relu_kernel<<<1024, 256, 0, stream>>>(S, P3, 262144, 8, 0);

  // rpn shared conv (relu)
  wsplit_kernel<<<dim3(4, 4, 9), 256, 0, stream>>>(w_rpn, WT, 256, 256, 9);
  conv_mfma<<<dim3(32, 2, 8), 256, 0, stream>>>(
      P3, WT, S, 64, 64, 256, 6, 256, 1, 1, 32, 4096, 0);
  reduce_relu_kernel<<<1024, 256, 0, stream>>>(S, T, 262144, 8, 1);

  // obj head + sigmoid, then NMS
  obj_sigmoid_kernel<<<64, 256, 0, stream>>>(T, w_obj, SC);
  nms_kernel<<<1, 256, 0, stream>>>(SC, out);
}